// Round 1
// baseline (670.394 us; speedup 1.0000x reference)
//
#include <hip/hip_runtime.h>

#define HD 4
#define D 64
#define NHD 256   // HD*D
#define N_IN 256

// ---------------- GEMM: hp = h @ W  (M x 256) @ (256 x 256) fp32 ----------------
constexpr int BM = 64, BN = 64, BK = 16;

__global__ __launch_bounds__(256) void gemm_kernel(const float* __restrict__ A,
                                                   const float* __restrict__ B,
                                                   float* __restrict__ C, int M) {
  __shared__ float As[BK][BM + 4];   // transposed: As[k][m]; row = 68 floats = 272B (16B mult)
  __shared__ float Bs[BK][BN];       // row = 256B
  const int tx = threadIdx.x, ty = threadIdx.y;
  const int tid = ty * 16 + tx;
  const int row0 = blockIdx.x * BM, col0 = blockIdx.y * BN;
  float acc[4][4] = {};
  const int ar = tid >> 2, aq = tid & 3;    // A tile: 64 rows x 4 float4
  const int br = tid >> 4, bq = tid & 15;   // B tile: 16 rows x 16 float4

  for (int k0 = 0; k0 < N_IN; k0 += BK) {
    float4 a4;
    if (row0 + ar < M)
      a4 = *(const float4*)&A[(size_t)(row0 + ar) * N_IN + k0 + aq * 4];
    else
      a4 = make_float4(0.f, 0.f, 0.f, 0.f);
    float4 b4 = *(const float4*)&B[(size_t)(k0 + br) * NHD + col0 + bq * 4];
    __syncthreads();   // previous iter's LDS reads done
    As[aq * 4 + 0][ar] = a4.x;
    As[aq * 4 + 1][ar] = a4.y;
    As[aq * 4 + 2][ar] = a4.z;
    As[aq * 4 + 3][ar] = a4.w;
    *(float4*)&Bs[br][bq * 4] = b4;
    __syncthreads();
#pragma unroll
    for (int kk = 0; kk < BK; ++kk) {
      float4 av = *(float4*)&As[kk][ty * 4];
      float4 bv = *(float4*)&Bs[kk][tx * 4];
      float a_[4] = {av.x, av.y, av.z, av.w};
      float b_[4] = {bv.x, bv.y, bv.z, bv.w};
#pragma unroll
      for (int i = 0; i < 4; ++i)
#pragma unroll
        for (int j = 0; j < 4; ++j) acc[i][j] += a_[i] * b_[j];
    }
  }
#pragma unroll
  for (int i = 0; i < 4; ++i) {
    int r = row0 + ty * 4 + i;
    if (r < M) {
      float4 o = make_float4(acc[i][0], acc[i][1], acc[i][2], acc[i][3]);
      *(float4*)&C[(size_t)r * NHD + col0 + tx * 4] = o;
    }
  }
}

// ------------- per-node attention coefficients: s[n,h], t[n,h] -------------
__global__ __launch_bounds__(256) void attn_coef_kernel(const float* __restrict__ hp,
                                                        const float* __restrict__ a_src,
                                                        const float* __restrict__ a_dst,
                                                        float* __restrict__ s,
                                                        float* __restrict__ t) {
  const int node = blockIdx.x;
  const int lane = threadIdx.x & 63, h = threadIdx.x >> 6;
  float v = hp[(size_t)node * NHD + h * D + lane];
  float sv = v * a_src[h * D + lane];
  float tv = v * a_dst[h * D + lane];
#pragma unroll
  for (int off = 32; off > 0; off >>= 1) {
    sv += __shfl_xor(sv, off);
    tv += __shfl_xor(tv, off);
  }
  if (lane == 0) {
    s[node * HD + h] = sv;
    t[node * HD + h] = tv;
  }
}

// ------------- init: zero e_sum and deg (ws is poisoned 0xAA every call) -------------
__global__ void init_kernel(float* __restrict__ e_sum, int* __restrict__ deg, int n) {
  int i = blockIdx.x * blockDim.x + threadIdx.x;
  if (i < n * HD) e_sum[i] = 0.f;
  if (i < n) deg[i] = 0;
}

// ------------- in-degree count -------------
__global__ void degree_kernel(const int* __restrict__ ei, int* __restrict__ deg, int E) {
  int e = blockIdx.x * blockDim.x + threadIdx.x;
  if (e < E) atomicAdd(&deg[ei[E + e]], 1);
}

// ------------- single-block exclusive scan of deg -> row_ptr, cursor -------------
__global__ __launch_bounds__(1024) void scan_kernel(const int* __restrict__ deg,
                                                    int* __restrict__ row_ptr,
                                                    int* __restrict__ cursor, int n) {
  __shared__ int wsum[16];
  __shared__ int carryS;
  const int tid = threadIdx.x;
  const int lane = tid & 63, wid = tid >> 6;
  if (tid == 0) carryS = 0;
  __syncthreads();
  for (int base = 0; base < n; base += 1024) {
    int i = base + tid;
    int v = (i < n) ? deg[i] : 0;
    int x = v;
#pragma unroll
    for (int off = 1; off < 64; off <<= 1) {
      int y = __shfl_up(x, off);
      if (lane >= off) x += y;
    }
    if (lane == 63) wsum[wid] = x;
    __syncthreads();
    if (tid < 16) {
      int w = wsum[tid];
#pragma unroll
      for (int off = 1; off < 16; off <<= 1) {
        int y = __shfl_up(w, off);
        if (tid >= off) w += y;
      }
      wsum[tid] = w;
    }
    __syncthreads();
    int wbase = (wid > 0) ? wsum[wid - 1] : 0;
    int incl = carryS + wbase + x;
    int excl = incl - v;
    if (i < n) {
      row_ptr[i] = excl;
      cursor[i] = excl;
    }
    __syncthreads();   // all reads of carryS/wsum done
    if (tid == 1023) carryS = incl;
    __syncthreads();
  }
  if (tid == 0) row_ptr[n] = carryS;
}

// ------------- per-edge: scatter into CSR, compute exp(logit), accumulate e_sum -------------
__global__ void edge_kernel(const int* __restrict__ ei, const float* __restrict__ s,
                            const float* __restrict__ t, int* __restrict__ cursor,
                            int* __restrict__ csr_src, float* __restrict__ csr_ex,
                            float* __restrict__ e_sum, int E) {
  int e = blockIdx.x * blockDim.x + threadIdx.x;
  if (e >= E) return;
  int sn = ei[e], dn = ei[E + e];
  int pos = atomicAdd(&cursor[dn], 1);
  csr_src[pos] = sn;
#pragma unroll
  for (int h = 0; h < HD; ++h) {
    float lg = s[sn * HD + h] + t[dn * HD + h];
    lg = fmaxf(lg, 0.2f * lg);           // leaky_relu(x, 0.2) since slope < 1
    float ex = __expf(lg);               // no max-subtract: |logit| <~ 8, exp safe in fp32
    csr_ex[(size_t)pos * HD + h] = ex;
    atomicAdd(&e_sum[dn * HD + h], ex);
  }
}

// ------------- per-dst aggregation: out[n, h*64+d] = sum alpha * hp[src] -------------
__global__ __launch_bounds__(256) void aggregate_kernel(const int* __restrict__ row_ptr,
                                                        const int* __restrict__ csr_src,
                                                        const float* __restrict__ csr_ex,
                                                        const float* __restrict__ e_sum,
                                                        const float* __restrict__ hp,
                                                        float* __restrict__ out) {
  const int node = blockIdx.x;
  const int tid = threadIdx.x;   // 0..255 == h*64 + d
  const int h = tid >> 6;
  const int beg = row_ptr[node], end = row_ptr[node + 1];
  const float inv = 1.0f / (e_sum[node * HD + h] + 1e-16f);
  float acc = 0.f;
  for (int i = beg; i < end; ++i) {
    int sn = csr_src[i];
    float a = csr_ex[(size_t)i * HD + h] * inv;
    acc += a * hp[(size_t)sn * NHD + tid];
  }
  out[(size_t)node * NHD + tid] = acc;
}

extern "C" void kernel_launch(void* const* d_in, const int* in_sizes, int n_in,
                              void* d_out, int out_size, void* d_ws, size_t ws_size,
                              hipStream_t stream) {
  const float* h_ptr  = (const float*)d_in[0];
  const int*   ei     = (const int*)d_in[1];
  const float* W      = (const float*)d_in[2];
  const float* a_src  = (const float*)d_in[3];
  const float* a_dst  = (const float*)d_in[4];
  float* out = (float*)d_out;

  const int N = in_sizes[0] / N_IN;     // 50000
  const int E = in_sizes[1] / 2;        // 800000

  auto align256 = [](size_t x) { return (x + 255) & ~size_t(255); };
  char* base = (char*)d_ws;
  size_t off = 0;
  float* hp      = (float*)(base + off); off += align256((size_t)N * NHD * 4);
  float* s       = (float*)(base + off); off += align256((size_t)N * HD * 4);
  float* t       = (float*)(base + off); off += align256((size_t)N * HD * 4);
  float* e_sum   = (float*)(base + off); off += align256((size_t)N * HD * 4);
  float* csr_ex  = (float*)(base + off); off += align256((size_t)E * HD * 4);
  int*   deg     = (int*)(base + off);   off += align256((size_t)N * 4);
  int*   row_ptr = (int*)(base + off);   off += align256((size_t)(N + 1) * 4);
  int*   cursor  = (int*)(base + off);   off += align256((size_t)N * 4);
  int*   csr_src = (int*)(base + off);   off += align256((size_t)E * 4);

  // 1. zero e_sum / deg
  {
    int total = N * HD;
    init_kernel<<<(total + 255) / 256, 256, 0, stream>>>(e_sum, deg, N);
  }
  // 2. GEMM hp = h @ W
  {
    dim3 grid((N + BM - 1) / BM, NHD / BN);
    dim3 block(16, 16);
    gemm_kernel<<<grid, block, 0, stream>>>(h_ptr, W, hp, N);
  }
  // 3. per-node s, t
  attn_coef_kernel<<<N, 256, 0, stream>>>(hp, a_src, a_dst, s, t);
  // 4. in-degrees
  degree_kernel<<<(E + 255) / 256, 256, 0, stream>>>(ei, deg, E);
  // 5. prefix sum -> row_ptr, cursor
  scan_kernel<<<1, 1024, 0, stream>>>(deg, row_ptr, cursor, N);
  // 6. per-edge scatter + exp + e_sum
  edge_kernel<<<(E + 255) / 256, 256, 0, stream>>>(ei, s, t, cursor, csr_src, csr_ex, e_sum, E);
  // 7. per-dst aggregation
  aggregate_kernel<<<N, 256, 0, stream>>>(row_ptr, csr_src, csr_ex, e_sum, hp, out);
}

// Round 2
// 521.770 us; speedup vs baseline: 1.2848x; 1.2848x over previous
//
#include <hip/hip_runtime.h>

#define HD 4
#define D 64
#define NHD 256   // HD*D
#define N_IN 256

// ---------------- GEMM: hp = h @ W  (M x 256) @ (256 x 256) fp32 ----------------
constexpr int BM = 64, BN = 64, BK = 16;

__global__ __launch_bounds__(256) void gemm_kernel(const float* __restrict__ A,
                                                   const float* __restrict__ B,
                                                   float* __restrict__ C, int M) {
  __shared__ float As[BK][BM + 4];   // transposed: As[k][m]; row = 68 floats = 272B (16B mult)
  __shared__ float Bs[BK][BN];       // row = 256B
  const int tx = threadIdx.x, ty = threadIdx.y;
  const int tid = ty * 16 + tx;
  const int row0 = blockIdx.x * BM, col0 = blockIdx.y * BN;
  float acc[4][4] = {};
  const int ar = tid >> 2, aq = tid & 3;    // A tile: 64 rows x 4 float4
  const int br = tid >> 4, bq = tid & 15;   // B tile: 16 rows x 16 float4

  for (int k0 = 0; k0 < N_IN; k0 += BK) {
    float4 a4;
    if (row0 + ar < M)
      a4 = *(const float4*)&A[(size_t)(row0 + ar) * N_IN + k0 + aq * 4];
    else
      a4 = make_float4(0.f, 0.f, 0.f, 0.f);
    float4 b4 = *(const float4*)&B[(size_t)(k0 + br) * NHD + col0 + bq * 4];
    __syncthreads();   // previous iter's LDS reads done
    As[aq * 4 + 0][ar] = a4.x;
    As[aq * 4 + 1][ar] = a4.y;
    As[aq * 4 + 2][ar] = a4.z;
    As[aq * 4 + 3][ar] = a4.w;
    *(float4*)&Bs[br][bq * 4] = b4;
    __syncthreads();
#pragma unroll
    for (int kk = 0; kk < BK; ++kk) {
      float4 av = *(float4*)&As[kk][ty * 4];
      float4 bv = *(float4*)&Bs[kk][tx * 4];
      float a_[4] = {av.x, av.y, av.z, av.w};
      float b_[4] = {bv.x, bv.y, bv.z, bv.w};
#pragma unroll
      for (int i = 0; i < 4; ++i)
#pragma unroll
        for (int j = 0; j < 4; ++j) acc[i][j] += a_[i] * b_[j];
    }
  }
#pragma unroll
  for (int i = 0; i < 4; ++i) {
    int r = row0 + ty * 4 + i;
    if (r < M) {
      float4 o = make_float4(acc[i][0], acc[i][1], acc[i][2], acc[i][3]);
      *(float4*)&C[(size_t)r * NHD + col0 + tx * 4] = o;
    }
  }
}

// ------------- per-node attention coefficients: s[n,h], t[n,h] -------------
__global__ __launch_bounds__(256) void attn_coef_kernel(const float* __restrict__ hp,
                                                        const float* __restrict__ a_src,
                                                        const float* __restrict__ a_dst,
                                                        float* __restrict__ s,
                                                        float* __restrict__ t) {
  const int node = blockIdx.x;
  const int lane = threadIdx.x & 63, h = threadIdx.x >> 6;
  float v = hp[(size_t)node * NHD + h * D + lane];
  float sv = v * a_src[h * D + lane];
  float tv = v * a_dst[h * D + lane];
#pragma unroll
  for (int off = 32; off > 0; off >>= 1) {
    sv += __shfl_xor(sv, off);
    tv += __shfl_xor(tv, off);
  }
  if (lane == 0) {
    s[node * HD + h] = sv;
    t[node * HD + h] = tv;
  }
}

// ------------- init: zero deg (ws is poisoned 0xAA every call) -------------
__global__ void init_kernel(int* __restrict__ deg, int n) {
  int i = blockIdx.x * blockDim.x + threadIdx.x;
  if (i < n) deg[i] = 0;
}

// ------------- in-degree count -------------
__global__ void degree_kernel(const int* __restrict__ ei, int* __restrict__ deg, int E) {
  int e = blockIdx.x * blockDim.x + threadIdx.x;
  if (e < E) atomicAdd(&deg[ei[E + e]], 1);
}

// ------------- single-block exclusive scan of deg -> row_ptr, cursor -------------
__global__ __launch_bounds__(1024) void scan_kernel(const int* __restrict__ deg,
                                                    int* __restrict__ row_ptr,
                                                    int* __restrict__ cursor, int n) {
  __shared__ int wsum[16];
  __shared__ int carryS;
  const int tid = threadIdx.x;
  const int lane = tid & 63, wid = tid >> 6;
  if (tid == 0) carryS = 0;
  __syncthreads();
  for (int base = 0; base < n; base += 1024) {
    int i = base + tid;
    int v = (i < n) ? deg[i] : 0;
    int x = v;
#pragma unroll
    for (int off = 1; off < 64; off <<= 1) {
      int y = __shfl_up(x, off);
      if (lane >= off) x += y;
    }
    if (lane == 63) wsum[wid] = x;
    __syncthreads();
    if (tid < 16) {
      int w = wsum[tid];
#pragma unroll
      for (int off = 1; off < 16; off <<= 1) {
        int y = __shfl_up(w, off);
        if (tid >= off) w += y;
      }
      wsum[tid] = w;
    }
    __syncthreads();
    int wbase = (wid > 0) ? wsum[wid - 1] : 0;
    int incl = carryS + wbase + x;
    int excl = incl - v;
    if (i < n) {
      row_ptr[i] = excl;
      cursor[i] = excl;
    }
    __syncthreads();   // all reads of carryS/wsum done
    if (tid == 1023) carryS = incl;
    __syncthreads();
  }
  if (tid == 0) row_ptr[n] = carryS;
}

// ------------- per-edge scatter into CSR (src index only) -------------
__global__ void scatter_kernel(const int* __restrict__ ei, int* __restrict__ cursor,
                               int* __restrict__ csr_src, int E) {
  int e = blockIdx.x * blockDim.x + threadIdx.x;
  if (e >= E) return;
  int sn = ei[e], dn = ei[E + e];
  int pos = atomicAdd(&cursor[dn], 1);
  csr_src[pos] = sn;
}

// ------------- per-dst aggregation with inline softmax -------------
// out[n, h*64+d] = (sum_e ex_e * hp[src_e, h*64+d]) / (sum_e ex_e + 1e-16)
// ex computed per-wave (64 lanes redundant = free in SIMD lockstep).
__global__ __launch_bounds__(256) void aggregate_kernel(const int* __restrict__ row_ptr,
                                                        const int* __restrict__ csr_src,
                                                        const float* __restrict__ s,
                                                        const float* __restrict__ t,
                                                        const float* __restrict__ hp,
                                                        float* __restrict__ out) {
  const int node = blockIdx.x;
  const int tid = threadIdx.x;   // 0..255 == h*64 + d
  const int h = tid >> 6;
  const int beg = row_ptr[node], end = row_ptr[node + 1];
  const float tn = t[node * HD + h];
  float num = 0.f, den = 0.f;
  int i = beg;
  int sn = (i < end) ? csr_src[i] : 0;
  for (; i < end; ++i) {
    int sn_next = (i + 1 < end) ? csr_src[i + 1] : 0;   // prefetch next index
    float lg = s[sn * HD + h] + tn;
    lg = fmaxf(lg, 0.2f * lg);           // leaky_relu, slope 0.2 < 1
    float ex = __expf(lg);               // |logit| small; exp safe in fp32, no max-subtract
    den += ex;
    num += ex * hp[(size_t)sn * NHD + tid];
    sn = sn_next;
  }
  out[(size_t)node * NHD + tid] = num / (den + 1e-16f);
}

extern "C" void kernel_launch(void* const* d_in, const int* in_sizes, int n_in,
                              void* d_out, int out_size, void* d_ws, size_t ws_size,
                              hipStream_t stream) {
  const float* h_ptr  = (const float*)d_in[0];
  const int*   ei     = (const int*)d_in[1];
  const float* W      = (const float*)d_in[2];
  const float* a_src  = (const float*)d_in[3];
  const float* a_dst  = (const float*)d_in[4];
  float* out = (float*)d_out;

  const int N = in_sizes[0] / N_IN;     // 50000
  const int E = in_sizes[1] / 2;        // 800000

  auto align256 = [](size_t x) { return (x + 255) & ~size_t(255); };
  char* base = (char*)d_ws;
  size_t off = 0;
  float* hp      = (float*)(base + off); off += align256((size_t)N * NHD * 4);
  float* s       = (float*)(base + off); off += align256((size_t)N * HD * 4);
  float* t       = (float*)(base + off); off += align256((size_t)N * HD * 4);
  int*   deg     = (int*)(base + off);   off += align256((size_t)N * 4);
  int*   row_ptr = (int*)(base + off);   off += align256((size_t)(N + 1) * 4);
  int*   cursor  = (int*)(base + off);   off += align256((size_t)N * 4);
  int*   csr_src = (int*)(base + off);   off += align256((size_t)E * 4);

  // 1. zero deg
  init_kernel<<<(N + 255) / 256, 256, 0, stream>>>(deg, N);
  // 2. GEMM hp = h @ W
  {
    dim3 grid((N + BM - 1) / BM, NHD / BN);
    dim3 block(16, 16);
    gemm_kernel<<<grid, block, 0, stream>>>(h_ptr, W, hp, N);
  }
  // 3. per-node s, t
  attn_coef_kernel<<<N, 256, 0, stream>>>(hp, a_src, a_dst, s, t);
  // 4. in-degrees
  degree_kernel<<<(E + 255) / 256, 256, 0, stream>>>(ei, deg, E);
  // 5. prefix sum -> row_ptr, cursor
  scan_kernel<<<1, 1024, 0, stream>>>(deg, row_ptr, cursor, N);
  // 6. per-edge scatter (src only)
  scatter_kernel<<<(E + 255) / 256, 256, 0, stream>>>(ei, cursor, csr_src, E);
  // 7. per-dst aggregation with inline softmax
  aggregate_kernel<<<N, 256, 0, stream>>>(row_ptr, csr_src, s, t, hp, out);
}

// Round 3
// 386.346 us; speedup vs baseline: 1.7352x; 1.3505x over previous
//
#include <hip/hip_runtime.h>

#define HD 4
#define D 64
#define NHD 256   // HD*D
#define N_IN 256

__device__ __forceinline__ unsigned short f2bf(float f) {
  unsigned u = __float_as_uint(f);
  unsigned r = (u + 0x7fffu + ((u >> 16) & 1u)) >> 16;   // RNE
  return (unsigned short)r;
}
__device__ __forceinline__ float bf2f(unsigned short u) {
  return __uint_as_float((unsigned)u << 16);
}

// ---------------- GEMM: hp16 = bf16(h @ W), fused s/t epilogue ----------------
// (M x 256) @ (256 x 256) fp32 compute. BN=64=D -> blockIdx.y == head.
constexpr int BM = 64, BN = 64, BK = 16;

__global__ __launch_bounds__(256) void gemm_fused_kernel(
    const float* __restrict__ A, const float* __restrict__ B,
    const float* __restrict__ a_src, const float* __restrict__ a_dst,
    unsigned short* __restrict__ hp16, float* __restrict__ s_out,
    float* __restrict__ t_out, int M) {
  __shared__ float As[BK][BM + 4];   // transposed: As[k][m]; 68 floats/row (16B mult)
  __shared__ float Bs[BK][BN];
  const int tx = threadIdx.x, ty = threadIdx.y;
  const int tid = ty * 16 + tx;
  const int row0 = blockIdx.x * BM, col0 = blockIdx.y * BN;
  float acc[4][4] = {};
  const int ar = tid >> 2, aq = tid & 3;    // A tile: 64 rows x 4 float4
  const int br = tid >> 4, bq = tid & 15;   // B tile: 16 rows x 16 float4

  for (int k0 = 0; k0 < N_IN; k0 += BK) {
    float4 a4;
    if (row0 + ar < M)
      a4 = *(const float4*)&A[(size_t)(row0 + ar) * N_IN + k0 + aq * 4];
    else
      a4 = make_float4(0.f, 0.f, 0.f, 0.f);
    float4 b4 = *(const float4*)&B[(size_t)(k0 + br) * NHD + col0 + bq * 4];
    __syncthreads();
    As[aq * 4 + 0][ar] = a4.x;
    As[aq * 4 + 1][ar] = a4.y;
    As[aq * 4 + 2][ar] = a4.z;
    As[aq * 4 + 3][ar] = a4.w;
    *(float4*)&Bs[br][bq * 4] = b4;
    __syncthreads();
#pragma unroll
    for (int kk = 0; kk < BK; ++kk) {
      float4 av = *(float4*)&As[kk][ty * 4];
      float4 bv = *(float4*)&Bs[kk][tx * 4];
      float a_[4] = {av.x, av.y, av.z, av.w};
      float b_[4] = {bv.x, bv.y, bv.z, bv.w};
#pragma unroll
      for (int i = 0; i < 4; ++i)
#pragma unroll
        for (int j = 0; j < 4; ++j) acc[i][j] += a_[i] * b_[j];
    }
  }

  // epilogue: bf16 store + fused per-row s/t (this block covers all of head `by`)
  const int head = blockIdx.y;
  const float4 asv = *(const float4*)&a_src[head * D + tx * 4];
  const float4 adv = *(const float4*)&a_dst[head * D + tx * 4];
#pragma unroll
  for (int i = 0; i < 4; ++i) {
    const int r = row0 + ty * 4 + i;
    float sv = acc[i][0] * asv.x + acc[i][1] * asv.y + acc[i][2] * asv.z + acc[i][3] * asv.w;
    float tv = acc[i][0] * adv.x + acc[i][1] * adv.y + acc[i][2] * adv.z + acc[i][3] * adv.w;
    // reduce across the 16 tx-lanes (lane = (ty&3)*16 + tx, so xor 1,2,4,8 stays in-group)
#pragma unroll
    for (int m = 1; m < 16; m <<= 1) {
      sv += __shfl_xor(sv, m);
      tv += __shfl_xor(tv, m);
    }
    if (r < M) {
      ushort4 u;
      u.x = f2bf(acc[i][0]);
      u.y = f2bf(acc[i][1]);
      u.z = f2bf(acc[i][2]);
      u.w = f2bf(acc[i][3]);
      *(ushort4*)&hp16[(size_t)r * NHD + col0 + tx * 4] = u;
      if (tx == 0) {
        s_out[r * HD + head] = sv;
        t_out[r * HD + head] = tv;
      }
    }
  }
}

// ------------- init: zero deg (ws is poisoned 0xAA every call) -------------
__global__ void init_kernel(int* __restrict__ deg, int n) {
  int i = blockIdx.x * blockDim.x + threadIdx.x;
  if (i < n) deg[i] = 0;
}

// ------------- in-degree count -------------
__global__ void degree_kernel(const int* __restrict__ ei, int* __restrict__ deg, int E) {
  int e = blockIdx.x * blockDim.x + threadIdx.x;
  if (e < E) atomicAdd(&deg[ei[E + e]], 1);
}

// ------------- single-block exclusive scan of deg -> row_ptr, cursor -------------
__global__ __launch_bounds__(1024) void scan_kernel(const int* __restrict__ deg,
                                                    int* __restrict__ row_ptr,
                                                    int* __restrict__ cursor, int n) {
  __shared__ int wsum[16];
  __shared__ int carryS;
  const int tid = threadIdx.x;
  const int lane = tid & 63, wid = tid >> 6;
  if (tid == 0) carryS = 0;
  __syncthreads();
  for (int base = 0; base < n; base += 1024) {
    int i = base + tid;
    int v = (i < n) ? deg[i] : 0;
    int x = v;
#pragma unroll
    for (int off = 1; off < 64; off <<= 1) {
      int y = __shfl_up(x, off);
      if (lane >= off) x += y;
    }
    if (lane == 63) wsum[wid] = x;
    __syncthreads();
    if (tid < 16) {
      int w = wsum[tid];
#pragma unroll
      for (int off = 1; off < 16; off <<= 1) {
        int y = __shfl_up(w, off);
        if (tid >= off) w += y;
      }
      wsum[tid] = w;
    }
    __syncthreads();
    int wbase = (wid > 0) ? wsum[wid - 1] : 0;
    int incl = carryS + wbase + x;
    int excl = incl - v;
    if (i < n) {
      row_ptr[i] = excl;
      cursor[i] = excl;
    }
    __syncthreads();
    if (tid == 1023) carryS = incl;
    __syncthreads();
  }
  if (tid == 0) row_ptr[n] = carryS;
}

// ------------- per-edge scatter into CSR (src index only) -------------
__global__ void scatter_kernel(const int* __restrict__ ei, int* __restrict__ cursor,
                               int* __restrict__ csr_src, int E) {
  int e = blockIdx.x * blockDim.x + threadIdx.x;
  if (e >= E) return;
  int sn = ei[e], dn = ei[E + e];
  int pos = atomicAdd(&cursor[dn], 1);
  csr_src[pos] = sn;
}

// ------------- per-dst aggregation: 1 wave per node, 4 dims per lane -------------
// out[n, lane*4 .. +3] = (sum_e ex_e * hp16[src_e, :]) / (sum_e ex_e + 1e-16)
__global__ __launch_bounds__(256) void aggregate_kernel(
    const int* __restrict__ row_ptr, const int* __restrict__ csr_src,
    const float* __restrict__ s, const float* __restrict__ t,
    const unsigned short* __restrict__ hp16, float* __restrict__ out, int N) {
  const int wave = threadIdx.x >> 6;
  const int lane = threadIdx.x & 63;
  const int node = blockIdx.x * 4 + wave;
  if (node >= N) return;
  const int h = lane >> 4;        // head of dims [lane*4, lane*4+4)
  const int d0 = lane * 4;
  const int beg = row_ptr[node], end = row_ptr[node + 1];
  const float tn = t[node * HD + h];
  float num0 = 0.f, num1 = 0.f, num2 = 0.f, num3 = 0.f, den = 0.f;
  int i = beg;
  for (; i + 2 <= end; i += 2) {   // 2 independent gathers in flight
    int sn0 = csr_src[i], sn1 = csr_src[i + 1];
    ushort4 v0 = *(const ushort4*)&hp16[(size_t)sn0 * NHD + d0];
    ushort4 v1 = *(const ushort4*)&hp16[(size_t)sn1 * NHD + d0];
    float lg0 = s[sn0 * HD + h] + tn;
    float lg1 = s[sn1 * HD + h] + tn;
    lg0 = fmaxf(lg0, 0.2f * lg0);
    lg1 = fmaxf(lg1, 0.2f * lg1);
    float ex0 = __expf(lg0), ex1 = __expf(lg1);
    den += ex0 + ex1;
    num0 += ex0 * bf2f(v0.x) + ex1 * bf2f(v1.x);
    num1 += ex0 * bf2f(v0.y) + ex1 * bf2f(v1.y);
    num2 += ex0 * bf2f(v0.z) + ex1 * bf2f(v1.z);
    num3 += ex0 * bf2f(v0.w) + ex1 * bf2f(v1.w);
  }
  if (i < end) {
    int sn0 = csr_src[i];
    ushort4 v0 = *(const ushort4*)&hp16[(size_t)sn0 * NHD + d0];
    float lg0 = s[sn0 * HD + h] + tn;
    lg0 = fmaxf(lg0, 0.2f * lg0);
    float ex0 = __expf(lg0);
    den += ex0;
    num0 += ex0 * bf2f(v0.x);
    num1 += ex0 * bf2f(v0.y);
    num2 += ex0 * bf2f(v0.z);
    num3 += ex0 * bf2f(v0.w);
  }
  const float inv = 1.0f / (den + 1e-16f);
  float4 o = make_float4(num0 * inv, num1 * inv, num2 * inv, num3 * inv);
  *(float4*)&out[(size_t)node * NHD + d0] = o;
}

extern "C" void kernel_launch(void* const* d_in, const int* in_sizes, int n_in,
                              void* d_out, int out_size, void* d_ws, size_t ws_size,
                              hipStream_t stream) {
  const float* h_ptr  = (const float*)d_in[0];
  const int*   ei     = (const int*)d_in[1];
  const float* W      = (const float*)d_in[2];
  const float* a_src  = (const float*)d_in[3];
  const float* a_dst  = (const float*)d_in[4];
  float* out = (float*)d_out;

  const int N = in_sizes[0] / N_IN;     // 50000
  const int E = in_sizes[1] / 2;        // 800000

  auto align256 = [](size_t x) { return (x + 255) & ~size_t(255); };
  char* base = (char*)d_ws;
  size_t off = 0;
  unsigned short* hp16 = (unsigned short*)(base + off); off += align256((size_t)N * NHD * 2);
  float* s       = (float*)(base + off); off += align256((size_t)N * HD * 4);
  float* t       = (float*)(base + off); off += align256((size_t)N * HD * 4);
  int*   deg     = (int*)(base + off);   off += align256((size_t)N * 4);
  int*   row_ptr = (int*)(base + off);   off += align256((size_t)(N + 1) * 4);
  int*   cursor  = (int*)(base + off);   off += align256((size_t)N * 4);
  int*   csr_src = (int*)(base + off);   off += align256((size_t)E * 4);

  // 1. zero deg
  init_kernel<<<(N + 255) / 256, 256, 0, stream>>>(deg, N);
  // 2. GEMM hp16 = bf16(h @ W) with fused s/t
  {
    dim3 grid((N + BM - 1) / BM, NHD / BN);
    dim3 block(16, 16);
    gemm_fused_kernel<<<grid, block, 0, stream>>>(h_ptr, W, a_src, a_dst, hp16, s, t, N);
  }
  // 3. in-degrees
  degree_kernel<<<(E + 255) / 256, 256, 0, stream>>>(ei, deg, E);
  // 4. prefix sum -> row_ptr, cursor
  scan_kernel<<<1, 1024, 0, stream>>>(deg, row_ptr, cursor, N);
  // 5. per-edge scatter (src only)
  scatter_kernel<<<(E + 255) / 256, 256, 0, stream>>>(ei, cursor, csr_src, E);
  // 6. per-dst aggregation (1 wave/node, bf16 gather)
  aggregate_kernel<<<(N + 3) / 4, 256, 0, stream>>>(row_ptr, csr_src, s, t, hp16, out, N);
}

// Round 4
// 339.252 us; speedup vs baseline: 1.9761x; 1.1388x over previous
//
#include <hip/hip_runtime.h>

#define HD 4
#define D 64
#define NHD 256   // HD*D
#define N_IN 256

typedef __attribute__((ext_vector_type(8))) __bf16 bf16x8;
typedef __attribute__((ext_vector_type(4))) __bf16 bf16x4;
typedef __attribute__((ext_vector_type(4))) float f32x4;

// ---- W precompute: split-transpose W[k][n] -> WtH/WtL[n][k] (bf16 hi + lo) ----
__global__ void wsplit_kernel(const float* __restrict__ W, __bf16* __restrict__ WtH,
                              __bf16* __restrict__ WtL) {
  const int k = blockIdx.x, n = threadIdx.x;
  float w = W[k * NHD + n];           // coalesced read
  __bf16 hi = (__bf16)w;
  __bf16 lo = (__bf16)(w - (float)hi);
  WtH[n * N_IN + k] = hi;             // scattered 2B write; 64K elems, trivial
  WtL[n * N_IN + k] = lo;
}

// ---- MFMA GEMM: hp16 = bf16(h @ W), fused s/t epilogue ----
// tile 128x128, 4 waves in 2x2; wave computes 64x64 via 4x4 of 16x16x32 MFMAs.
// Precision: A rounded to bf16; B = Bhi + Blo (2 MFMA passes) ~ full fp32 B.
constexpr int AROW = 40;   // padded LDS row stride in bf16 (80B = 16B-multiple; 2-way banks = free)

__global__ __launch_bounds__(256) void gemm_mfma_kernel(
    const float* __restrict__ A, const __bf16* __restrict__ WtH,
    const __bf16* __restrict__ WtL, const float* __restrict__ a_src,
    const float* __restrict__ a_dst, __bf16* __restrict__ hp16,
    float* __restrict__ s_out, float* __restrict__ t_out, int M) {
  __shared__ __bf16 As[128 * AROW];
  __shared__ __bf16 BsH[128 * AROW];
  __shared__ __bf16 BsL[128 * AROW];
  const int tid = threadIdx.x;
  const int lane = tid & 63, wv = tid >> 6;
  const int wr = wv >> 1, wc = wv & 1;        // wave row/col in 2x2
  const int c15 = lane & 15, quad = lane >> 4;
  const int m0 = blockIdx.x * 128, n0 = blockIdx.y * 128;

  f32x4 acc[4][4];
#pragma unroll
  for (int i = 0; i < 4; ++i)
#pragma unroll
    for (int j = 0; j < 4; ++j) acc[i][j] = (f32x4){0.f, 0.f, 0.f, 0.f};

  // staging assignment: thread t covers row (t>>1), k-halves of 16 elems at (t&1)*16
  const int am = tid >> 1, aks = (tid & 1) * 16;
  const int gr = m0 + am;
  const bool arow_ok = (gr < M);
  const float* Arow = &A[(size_t)gr * N_IN];
  const __bf16* BHrow = &WtH[(size_t)(n0 + am) * N_IN];
  const __bf16* BLrow = &WtL[(size_t)(n0 + am) * N_IN];

  for (int kc = 0; kc < 8; ++kc) {
    const int k0 = kc * 32;
    float4 f0, f1, f2, f3;
    if (arow_ok) {
      f0 = *(const float4*)&Arow[k0 + aks + 0];
      f1 = *(const float4*)&Arow[k0 + aks + 4];
      f2 = *(const float4*)&Arow[k0 + aks + 8];
      f3 = *(const float4*)&Arow[k0 + aks + 12];
    } else {
      f0 = f1 = f2 = f3 = make_float4(0.f, 0.f, 0.f, 0.f);
    }
    bf16x8 bh0 = *(const bf16x8*)&BHrow[k0 + aks];
    bf16x8 bh1 = *(const bf16x8*)&BHrow[k0 + aks + 8];
    bf16x8 bl0 = *(const bf16x8*)&BLrow[k0 + aks];
    bf16x8 bl1 = *(const bf16x8*)&BLrow[k0 + aks + 8];

    __syncthreads();   // previous iteration's LDS reads complete
    bf16x8 a0, a1;
    a0[0] = (__bf16)f0.x; a0[1] = (__bf16)f0.y; a0[2] = (__bf16)f0.z; a0[3] = (__bf16)f0.w;
    a0[4] = (__bf16)f1.x; a0[5] = (__bf16)f1.y; a0[6] = (__bf16)f1.z; a0[7] = (__bf16)f1.w;
    a1[0] = (__bf16)f2.x; a1[1] = (__bf16)f2.y; a1[2] = (__bf16)f2.z; a1[3] = (__bf16)f2.w;
    a1[4] = (__bf16)f3.x; a1[5] = (__bf16)f3.y; a1[6] = (__bf16)f3.z; a1[7] = (__bf16)f3.w;
    *(bf16x8*)&As[am * AROW + aks + 0] = a0;
    *(bf16x8*)&As[am * AROW + aks + 8] = a1;
    *(bf16x8*)&BsH[am * AROW + aks + 0] = bh0;
    *(bf16x8*)&BsH[am * AROW + aks + 8] = bh1;
    *(bf16x8*)&BsL[am * AROW + aks + 0] = bl0;
    *(bf16x8*)&BsL[am * AROW + aks + 8] = bl1;
    __syncthreads();

    bf16x8 af[4], bfh[4], bfl[4];
#pragma unroll
    for (int i = 0; i < 4; ++i) {
      af[i]  = *(bf16x8*)&As[(wr * 64 + i * 16 + c15) * AROW + quad * 8];
      bfh[i] = *(bf16x8*)&BsH[(wc * 64 + i * 16 + c15) * AROW + quad * 8];
      bfl[i] = *(bf16x8*)&BsL[(wc * 64 + i * 16 + c15) * AROW + quad * 8];
    }
#pragma unroll
    for (int mi = 0; mi < 4; ++mi)
#pragma unroll
      for (int ni = 0; ni < 4; ++ni)
        acc[mi][ni] = __builtin_amdgcn_mfma_f32_16x16x32_bf16(af[mi], bfh[ni], acc[mi][ni], 0, 0, 0);
#pragma unroll
    for (int mi = 0; mi < 4; ++mi)
#pragma unroll
      for (int ni = 0; ni < 4; ++ni)
        acc[mi][ni] = __builtin_amdgcn_mfma_f32_16x16x32_bf16(af[mi], bfl[ni], acc[mi][ni], 0, 0, 0);
  }

  // ---- epilogue ----
  // wave's 64 cols = one head: head = by*2 + wc. C layout: col=c15, row=quad*4+reg.
  const int head = blockIdx.y * 2 + wc;
  float av[4], ad[4];
#pragma unroll
  for (int ni = 0; ni < 4; ++ni) {
    av[ni] = a_src[head * D + ni * 16 + c15];
    ad[ni] = a_dst[head * D + ni * 16 + c15];
  }
  const int row0w = m0 + wr * 64;
#pragma unroll
  for (int mi = 0; mi < 4; ++mi) {
#pragma unroll
    for (int j = 0; j < 4; ++j) {
      float ps = acc[mi][0][j] * av[0] + acc[mi][1][j] * av[1] +
                 acc[mi][2][j] * av[2] + acc[mi][3][j] * av[3];
      float pt = acc[mi][0][j] * ad[0] + acc[mi][1][j] * ad[1] +
                 acc[mi][2][j] * ad[2] + acc[mi][3][j] * ad[3];
#pragma unroll
      for (int m = 1; m < 16; m <<= 1) {   // reduce over the 16 col-lanes (xor stays in quad group)
        ps += __shfl_xor(ps, m);
        pt += __shfl_xor(pt, m);
      }
      const int row = row0w + mi * 16 + quad * 4 + j;
      if (c15 == 0 && row < M) {
        s_out[row * HD + head] = ps;
        t_out[row * HD + head] = pt;
      }
    }
    // hp16 stores
#pragma unroll
    for (int ni = 0; ni < 4; ++ni) {
#pragma unroll
      for (int j = 0; j < 4; ++j) {
        const int row = row0w + mi * 16 + quad * 4 + j;
        const int col = n0 + wc * 64 + ni * 16 + c15;
        if (row < M) hp16[(size_t)row * NHD + col] = (__bf16)acc[mi][ni][j];
      }
    }
  }
}

// ------------- init: zero deg (ws is poisoned 0xAA every call) -------------
__global__ void init_kernel(int* __restrict__ deg, int n) {
  int i = blockIdx.x * blockDim.x + threadIdx.x;
  if (i < n) deg[i] = 0;
}

// ------------- in-degree count -------------
__global__ void degree_kernel(const int* __restrict__ ei, int* __restrict__ deg, int E) {
  int e = blockIdx.x * blockDim.x + threadIdx.x;
  if (e < E) atomicAdd(&deg[ei[E + e]], 1);
}

// ------------- single-block exclusive scan of deg -> row_ptr, cursor -------------
__global__ __launch_bounds__(1024) void scan_kernel(const int* __restrict__ deg,
                                                    int* __restrict__ row_ptr,
                                                    int* __restrict__ cursor, int n) {
  __shared__ int wsum[16];
  __shared__ int carryS;
  const int tid = threadIdx.x;
  const int lane = tid & 63, wid = tid >> 6;
  if (tid == 0) carryS = 0;
  __syncthreads();
  for (int base = 0; base < n; base += 1024) {
    int i = base + tid;
    int v = (i < n) ? deg[i] : 0;
    int x = v;
#pragma unroll
    for (int off = 1; off < 64; off <<= 1) {
      int y = __shfl_up(x, off);
      if (lane >= off) x += y;
    }
    if (lane == 63) wsum[wid] = x;
    __syncthreads();
    if (tid < 16) {
      int w = wsum[tid];
#pragma unroll
      for (int off = 1; off < 16; off <<= 1) {
        int y = __shfl_up(w, off);
        if (tid >= off) w += y;
      }
      wsum[tid] = w;
    }
    __syncthreads();
    int wbase = (wid > 0) ? wsum[wid - 1] : 0;
    int incl = carryS + wbase + x;
    int excl = incl - v;
    if (i < n) {
      row_ptr[i] = excl;
      cursor[i] = excl;
    }
    __syncthreads();
    if (tid == 1023) carryS = incl;
    __syncthreads();
  }
  if (tid == 0) row_ptr[n] = carryS;
}

// ------------- per-edge scatter into CSR (src index only) -------------
__global__ void scatter_kernel(const int* __restrict__ ei, int* __restrict__ cursor,
                               int* __restrict__ csr_src, int E) {
  int e = blockIdx.x * blockDim.x + threadIdx.x;
  if (e >= E) return;
  int sn = ei[e], dn = ei[E + e];
  int pos = atomicAdd(&cursor[dn], 1);
  csr_src[pos] = sn;
}

// ------------- per-dst aggregation: 1 wave per node, 4 dims per lane -------------
__global__ __launch_bounds__(256) void aggregate_kernel(
    const int* __restrict__ row_ptr, const int* __restrict__ csr_src,
    const float* __restrict__ s, const float* __restrict__ t,
    const __bf16* __restrict__ hp16, float* __restrict__ out, int N) {
  const int wave = threadIdx.x >> 6;
  const int lane = threadIdx.x & 63;
  const int node = blockIdx.x * 4 + wave;
  if (node >= N) return;
  const int h = lane >> 4;        // head of dims [lane*4, lane*4+4)
  const int d0 = lane * 4;
  const int beg = row_ptr[node], end = row_ptr[node + 1];
  const float tn = t[node * HD + h];
  float num0 = 0.f, num1 = 0.f, num2 = 0.f, num3 = 0.f, den = 0.f;
  int i = beg;
  for (; i + 2 <= end; i += 2) {   // 2 independent gathers in flight
    int sn0 = csr_src[i], sn1 = csr_src[i + 1];
    bf16x4 v0 = *(const bf16x4*)&hp16[(size_t)sn0 * NHD + d0];
    bf16x4 v1 = *(const bf16x4*)&hp16[(size_t)sn1 * NHD + d0];
    float lg0 = s[sn0 * HD + h] + tn;
    float lg1 = s[sn1 * HD + h] + tn;
    lg0 = fmaxf(lg0, 0.2f * lg0);
    lg1 = fmaxf(lg1, 0.2f * lg1);
    float ex0 = __expf(lg0), ex1 = __expf(lg1);
    den += ex0 + ex1;
    num0 += ex0 * (float)v0[0] + ex1 * (float)v1[0];
    num1 += ex0 * (float)v0[1] + ex1 * (float)v1[1];
    num2 += ex0 * (float)v0[2] + ex1 * (float)v1[2];
    num3 += ex0 * (float)v0[3] + ex1 * (float)v1[3];
  }
  if (i < end) {
    int sn0 = csr_src[i];
    bf16x4 v0 = *(const bf16x4*)&hp16[(size_t)sn0 * NHD + d0];
    float lg0 = s[sn0 * HD + h] + tn;
    lg0 = fmaxf(lg0, 0.2f * lg0);
    float ex0 = __expf(lg0);
    den += ex0;
    num0 += ex0 * (float)v0[0];
    num1 += ex0 * (float)v0[1];
    num2 += ex0 * (float)v0[2];
    num3 += ex0 * (float)v0[3];
  }
  const float inv = 1.0f / (den + 1e-16f);
  float4 o = make_float4(num0 * inv, num1 * inv, num2 * inv, num3 * inv);
  *(float4*)&out[(size_t)node * NHD + d0] = o;
}

extern "C" void kernel_launch(void* const* d_in, const int* in_sizes, int n_in,
                              void* d_out, int out_size, void* d_ws, size_t ws_size,
                              hipStream_t stream) {
  const float* h_ptr  = (const float*)d_in[0];
  const int*   ei     = (const int*)d_in[1];
  const float* W      = (const float*)d_in[2];
  const float* a_src  = (const float*)d_in[3];
  const float* a_dst  = (const float*)d_in[4];
  float* out = (float*)d_out;

  const int N = in_sizes[0] / N_IN;     // 50000
  const int E = in_sizes[1] / 2;        // 800000

  auto align256 = [](size_t x) { return (x + 255) & ~size_t(255); };
  char* base = (char*)d_ws;
  size_t off = 0;
  __bf16* hp16 = (__bf16*)(base + off);  off += align256((size_t)N * NHD * 2);
  __bf16* WtH  = (__bf16*)(base + off);  off += align256((size_t)N_IN * NHD * 2);
  __bf16* WtL  = (__bf16*)(base + off);  off += align256((size_t)N_IN * NHD * 2);
  float* s       = (float*)(base + off); off += align256((size_t)N * HD * 4);
  float* t       = (float*)(base + off); off += align256((size_t)N * HD * 4);
  int*   deg     = (int*)(base + off);   off += align256((size_t)N * 4);
  int*   row_ptr = (int*)(base + off);   off += align256((size_t)(N + 1) * 4);
  int*   cursor  = (int*)(base + off);   off += align256((size_t)N * 4);
  int*   csr_src = (int*)(base + off);   off += align256((size_t)E * 4);

  // 1. zero deg
  init_kernel<<<(N + 255) / 256, 256, 0, stream>>>(deg, N);
  // 2. split-transpose W
  wsplit_kernel<<<N_IN, NHD, 0, stream>>>(W, WtH, WtL);
  // 3. MFMA GEMM with fused s/t + bf16 hp
  {
    dim3 grid((N + 127) / 128, NHD / 128);
    gemm_mfma_kernel<<<grid, 256, 0, stream>>>(h_ptr, WtH, WtL, a_src, a_dst, hp16, s, t, N);
  }
  // 4. in-degrees
  degree_kernel<<<(E + 255) / 256, 256, 0, stream>>>(ei, deg, E);
  // 5. prefix sum -> row_ptr, cursor
  scan_kernel<<<1, 1024, 0, stream>>>(deg, row_ptr, cursor, N);
  // 6. per-edge scatter (src only)
  scatter_kernel<<<(E + 255) / 256, 256, 0, stream>>>(ei, cursor, csr_src, E);
  // 7. per-dst aggregation (1 wave/node, bf16 gather)
  aggregate_kernel<<<(N + 3) / 4, 256, 0, stream>>>(row_ptr, csr_src, s, t, hp16, out, N);
}

// Round 5
// 291.999 us; speedup vs baseline: 2.2959x; 1.1618x over previous
//
#include <hip/hip_runtime.h>

#define HD 4
#define D 64
#define NHD 256   // HD*D
#define N_IN 256

typedef __attribute__((ext_vector_type(8))) __bf16 bf16x8;
typedef __attribute__((ext_vector_type(4))) __bf16 bf16x4;
typedef __attribute__((ext_vector_type(4))) float f32x4;

// ---- W precompute: split-transpose W[k][n] -> WtH/WtL[n][k] (bf16 hi + lo) ----
__global__ void wsplit_kernel(const float* __restrict__ W, __bf16* __restrict__ WtH,
                              __bf16* __restrict__ WtL) {
  const int k = blockIdx.x, n = threadIdx.x;
  float w = W[k * NHD + n];           // coalesced read
  __bf16 hi = (__bf16)w;
  __bf16 lo = (__bf16)(w - (float)hi);
  WtH[n * N_IN + k] = hi;             // scattered 2B write; 64K elems, trivial
  WtL[n * N_IN + k] = lo;
}

// ---- MFMA GEMM: hp16 = bf16(h @ W), fused s/t epilogue ----
// tile 128x128, 4 waves in 2x2; wave computes 64x64 via 4x4 of 16x16x32 MFMAs.
// Precision: A rounded to bf16; B = Bhi + Blo (2 MFMA passes) ~ full fp32 B.
constexpr int AROW = 40;   // padded LDS row stride in bf16 (80B = 16B-multiple; 2-way banks = free)

__global__ __launch_bounds__(256) void gemm_mfma_kernel(
    const float* __restrict__ A, const __bf16* __restrict__ WtH,
    const __bf16* __restrict__ WtL, const float* __restrict__ a_src,
    const float* __restrict__ a_dst, __bf16* __restrict__ hp16,
    float* __restrict__ s_out, float* __restrict__ t_out, int M) {
  __shared__ __bf16 As[128 * AROW];
  __shared__ __bf16 BsH[128 * AROW];
  __shared__ __bf16 BsL[128 * AROW];
  const int tid = threadIdx.x;
  const int lane = tid & 63, wv = tid >> 6;
  const int wr = wv >> 1, wc = wv & 1;        // wave row/col in 2x2
  const int c15 = lane & 15, quad = lane >> 4;
  const int m0 = blockIdx.x * 128, n0 = blockIdx.y * 128;

  f32x4 acc[4][4];
#pragma unroll
  for (int i = 0; i < 4; ++i)
#pragma unroll
    for (int j = 0; j < 4; ++j) acc[i][j] = (f32x4){0.f, 0.f, 0.f, 0.f};

  const int am = tid >> 1, aks = (tid & 1) * 16;
  const int gr = m0 + am;
  const bool arow_ok = (gr < M);
  const float* Arow = &A[(size_t)gr * N_IN];
  const __bf16* BHrow = &WtH[(size_t)(n0 + am) * N_IN];
  const __bf16* BLrow = &WtL[(size_t)(n0 + am) * N_IN];

  for (int kc = 0; kc < 8; ++kc) {
    const int k0 = kc * 32;
    float4 f0, f1, f2, f3;
    if (arow_ok) {
      f0 = *(const float4*)&Arow[k0 + aks + 0];
      f1 = *(const float4*)&Arow[k0 + aks + 4];
      f2 = *(const float4*)&Arow[k0 + aks + 8];
      f3 = *(const float4*)&Arow[k0 + aks + 12];
    } else {
      f0 = f1 = f2 = f3 = make_float4(0.f, 0.f, 0.f, 0.f);
    }
    bf16x8 bh0 = *(const bf16x8*)&BHrow[k0 + aks];
    bf16x8 bh1 = *(const bf16x8*)&BHrow[k0 + aks + 8];
    bf16x8 bl0 = *(const bf16x8*)&BLrow[k0 + aks];
    bf16x8 bl1 = *(const bf16x8*)&BLrow[k0 + aks + 8];

    __syncthreads();   // previous iteration's LDS reads complete
    bf16x8 a0, a1;
    a0[0] = (__bf16)f0.x; a0[1] = (__bf16)f0.y; a0[2] = (__bf16)f0.z; a0[3] = (__bf16)f0.w;
    a0[4] = (__bf16)f1.x; a0[5] = (__bf16)f1.y; a0[6] = (__bf16)f1.z; a0[7] = (__bf16)f1.w;
    a1[0] = (__bf16)f2.x; a1[1] = (__bf16)f2.y; a1[2] = (__bf16)f2.z; a1[3] = (__bf16)f2.w;
    a1[4] = (__bf16)f3.x; a1[5] = (__bf16)f3.y; a1[6] = (__bf16)f3.z; a1[7] = (__bf16)f3.w;
    *(bf16x8*)&As[am * AROW + aks + 0] = a0;
    *(bf16x8*)&As[am * AROW + aks + 8] = a1;
    *(bf16x8*)&BsH[am * AROW + aks + 0] = bh0;
    *(bf16x8*)&BsH[am * AROW + aks + 8] = bh1;
    *(bf16x8*)&BsL[am * AROW + aks + 0] = bl0;
    *(bf16x8*)&BsL[am * AROW + aks + 8] = bl1;
    __syncthreads();

    bf16x8 af[4], bfh[4], bfl[4];
#pragma unroll
    for (int i = 0; i < 4; ++i) {
      af[i]  = *(bf16x8*)&As[(wr * 64 + i * 16 + c15) * AROW + quad * 8];
      bfh[i] = *(bf16x8*)&BsH[(wc * 64 + i * 16 + c15) * AROW + quad * 8];
      bfl[i] = *(bf16x8*)&BsL[(wc * 64 + i * 16 + c15) * AROW + quad * 8];
    }
#pragma unroll
    for (int mi = 0; mi < 4; ++mi)
#pragma unroll
      for (int ni = 0; ni < 4; ++ni)
        acc[mi][ni] = __builtin_amdgcn_mfma_f32_16x16x32_bf16(af[mi], bfh[ni], acc[mi][ni], 0, 0, 0);
#pragma unroll
    for (int mi = 0; mi < 4; ++mi)
#pragma unroll
      for (int ni = 0; ni < 4; ++ni)
        acc[mi][ni] = __builtin_amdgcn_mfma_f32_16x16x32_bf16(af[mi], bfl[ni], acc[mi][ni], 0, 0, 0);
  }

  // ---- epilogue ----
  const int head = blockIdx.y * 2 + wc;
  float av[4], ad[4];
#pragma unroll
  for (int ni = 0; ni < 4; ++ni) {
    av[ni] = a_src[head * D + ni * 16 + c15];
    ad[ni] = a_dst[head * D + ni * 16 + c15];
  }
  const int row0w = m0 + wr * 64;
#pragma unroll
  for (int mi = 0; mi < 4; ++mi) {
#pragma unroll
    for (int j = 0; j < 4; ++j) {
      float ps = acc[mi][0][j] * av[0] + acc[mi][1][j] * av[1] +
                 acc[mi][2][j] * av[2] + acc[mi][3][j] * av[3];
      float pt = acc[mi][0][j] * ad[0] + acc[mi][1][j] * ad[1] +
                 acc[mi][2][j] * ad[2] + acc[mi][3][j] * ad[3];
#pragma unroll
      for (int m = 1; m < 16; m <<= 1) {
        ps += __shfl_xor(ps, m);
        pt += __shfl_xor(pt, m);
      }
      const int row = row0w + mi * 16 + quad * 4 + j;
      if (c15 == 0 && row < M) {
        s_out[row * HD + head] = ps;
        t_out[row * HD + head] = pt;
      }
    }
#pragma unroll
    for (int ni = 0; ni < 4; ++ni) {
#pragma unroll
      for (int j = 0; j < 4; ++j) {
        const int row = row0w + mi * 16 + quad * 4 + j;
        const int col = n0 + wc * 64 + ni * 16 + c15;
        if (row < M) hp16[(size_t)row * NHD + col] = (__bf16)acc[mi][ni][j];
      }
    }
  }
}

// ------------- init: zero deg (ws is poisoned 0xAA every call) -------------
__global__ void init_kernel(int* __restrict__ deg, int n) {
  int i = blockIdx.x * blockDim.x + threadIdx.x;
  if (i < n) deg[i] = 0;
}

// ------------- in-degree count -------------
__global__ void degree_kernel(const int* __restrict__ ei, int* __restrict__ deg, int E) {
  int e = blockIdx.x * blockDim.x + threadIdx.x;
  if (e < E) atomicAdd(&deg[ei[E + e]], 1);
}

// ------------- hierarchical scan: pass 1 (per-1024-chunk scan + block sums) -------------
// 256 threads, 4 elems/thread. partial[i] = exclusive prefix within chunk.
__global__ __launch_bounds__(256) void scan1_kernel(const int* __restrict__ deg,
                                                    int* __restrict__ partial,
                                                    int* __restrict__ blocksum, int n) {
  __shared__ int ws[4];
  const int tid = threadIdx.x, lane = tid & 63, wv = tid >> 6;
  const int base = blockIdx.x * 1024 + tid * 4;
  int v0 = (base + 0 < n) ? deg[base + 0] : 0;
  int v1 = (base + 1 < n) ? deg[base + 1] : 0;
  int v2 = (base + 2 < n) ? deg[base + 2] : 0;
  int v3 = (base + 3 < n) ? deg[base + 3] : 0;
  int sum = v0 + v1 + v2 + v3;
  int incl = sum;
#pragma unroll
  for (int off = 1; off < 64; off <<= 1) {
    int y = __shfl_up(incl, off);
    if (lane >= off) incl += y;
  }
  if (lane == 63) ws[wv] = incl;
  __syncthreads();
  int wbase = 0;
#pragma unroll
  for (int w = 0; w < 4; ++w)
    if (w < wv) wbase += ws[w];
  int excl = wbase + incl - sum;
  if (base + 0 < n) partial[base + 0] = excl;
  if (base + 1 < n) partial[base + 1] = excl + v0;
  if (base + 2 < n) partial[base + 2] = excl + v0 + v1;
  if (base + 3 < n) partial[base + 3] = excl + v0 + v1 + v2;
  if (tid == 0) {
    __syncthreads();   // no-op path safety: ws already populated above
  }
  if (tid == 255) blocksum[blockIdx.x] = wbase + incl;
}

// ------------- scan pass 2: one wave scans block sums (nb <= 64) -> blockoff, total -------------
__global__ __launch_bounds__(64) void scan2_kernel(const int* __restrict__ blocksum,
                                                   int* __restrict__ blockoff,
                                                   int* __restrict__ row_ptr_n, int nb) {
  const int lane = threadIdx.x;
  int v = (lane < nb) ? blocksum[lane] : 0;
  int incl = v;
#pragma unroll
  for (int off = 1; off < 64; off <<= 1) {
    int y = __shfl_up(incl, off);
    if (lane >= off) incl += y;
  }
  if (lane < nb) blockoff[lane] = incl - v;   // exclusive
  if (lane == 63) *row_ptr_n = incl;          // grand total -> row_ptr[n]
}

// ------------- scan pass 3: add block offsets, write row_ptr + cursor -------------
__global__ __launch_bounds__(256) void scan3_kernel(const int* __restrict__ partial,
                                                    const int* __restrict__ blockoff,
                                                    int* __restrict__ row_ptr,
                                                    int* __restrict__ cursor, int n) {
  const int base = blockIdx.x * 1024 + threadIdx.x * 4;
  const int off = blockoff[blockIdx.x];
  if (base + 3 < n) {
    int4 p = *(const int4*)&partial[base];
    int4 r = make_int4(p.x + off, p.y + off, p.z + off, p.w + off);
    *(int4*)&row_ptr[base] = r;
    *(int4*)&cursor[base] = r;
  } else {
    for (int j = 0; j < 4; ++j)
      if (base + j < n) {
        int r = partial[base + j] + off;
        row_ptr[base + j] = r;
        cursor[base + j] = r;
      }
  }
}

// ------------- per-edge scatter into CSR (src index only) -------------
__global__ void scatter_kernel(const int* __restrict__ ei, int* __restrict__ cursor,
                               int* __restrict__ csr_src, int E) {
  int e = blockIdx.x * blockDim.x + threadIdx.x;
  if (e >= E) return;
  int sn = ei[e], dn = ei[E + e];
  int pos = atomicAdd(&cursor[dn], 1);
  csr_src[pos] = sn;
}

// ------------- per-dst aggregation: 1 wave per node, 4 dims per lane, 4-deep MLP -------------
__global__ __launch_bounds__(256) void aggregate_kernel(
    const int* __restrict__ row_ptr, const int* __restrict__ csr_src,
    const float* __restrict__ s, const float* __restrict__ t,
    const __bf16* __restrict__ hp16, float* __restrict__ out, int N) {
  const int wave = threadIdx.x >> 6;
  const int lane = threadIdx.x & 63;
  const int node = blockIdx.x * 4 + wave;
  if (node >= N) return;
  const int h = lane >> 4;        // head of dims [lane*4, lane*4+4)
  const int d0 = lane * 4;
  const int beg = row_ptr[node], end = row_ptr[node + 1];
  const float tn = t[node * HD + h];
  float num0 = 0.f, num1 = 0.f, num2 = 0.f, num3 = 0.f, den = 0.f;
  int i = beg;
  for (; i + 4 <= end; i += 4) {   // 4 independent gathers in flight
    int sn0 = csr_src[i], sn1 = csr_src[i + 1], sn2 = csr_src[i + 2], sn3 = csr_src[i + 3];
    bf16x4 v0 = *(const bf16x4*)&hp16[(size_t)sn0 * NHD + d0];
    bf16x4 v1 = *(const bf16x4*)&hp16[(size_t)sn1 * NHD + d0];
    bf16x4 v2 = *(const bf16x4*)&hp16[(size_t)sn2 * NHD + d0];
    bf16x4 v3 = *(const bf16x4*)&hp16[(size_t)sn3 * NHD + d0];
    float lg0 = s[sn0 * HD + h] + tn;
    float lg1 = s[sn1 * HD + h] + tn;
    float lg2 = s[sn2 * HD + h] + tn;
    float lg3 = s[sn3 * HD + h] + tn;
    lg0 = fmaxf(lg0, 0.2f * lg0);
    lg1 = fmaxf(lg1, 0.2f * lg1);
    lg2 = fmaxf(lg2, 0.2f * lg2);
    lg3 = fmaxf(lg3, 0.2f * lg3);
    float ex0 = __expf(lg0), ex1 = __expf(lg1), ex2 = __expf(lg2), ex3 = __expf(lg3);
    den += (ex0 + ex1) + (ex2 + ex3);
    num0 += ex0 * (float)v0[0] + ex1 * (float)v1[0] + ex2 * (float)v2[0] + ex3 * (float)v3[0];
    num1 += ex0 * (float)v0[1] + ex1 * (float)v1[1] + ex2 * (float)v2[1] + ex3 * (float)v3[1];
    num2 += ex0 * (float)v0[2] + ex1 * (float)v1[2] + ex2 * (float)v2[2] + ex3 * (float)v3[2];
    num3 += ex0 * (float)v0[3] + ex1 * (float)v1[3] + ex2 * (float)v2[3] + ex3 * (float)v3[3];
  }
  for (; i < end; ++i) {
    int sn0 = csr_src[i];
    bf16x4 v0 = *(const bf16x4*)&hp16[(size_t)sn0 * NHD + d0];
    float lg0 = s[sn0 * HD + h] + tn;
    lg0 = fmaxf(lg0, 0.2f * lg0);
    float ex0 = __expf(lg0);
    den += ex0;
    num0 += ex0 * (float)v0[0];
    num1 += ex0 * (float)v0[1];
    num2 += ex0 * (float)v0[2];
    num3 += ex0 * (float)v0[3];
  }
  const float inv = 1.0f / (den + 1e-16f);
  float4 o = make_float4(num0 * inv, num1 * inv, num2 * inv, num3 * inv);
  *(float4*)&out[(size_t)node * NHD + d0] = o;
}

extern "C" void kernel_launch(void* const* d_in, const int* in_sizes, int n_in,
                              void* d_out, int out_size, void* d_ws, size_t ws_size,
                              hipStream_t stream) {
  const float* h_ptr  = (const float*)d_in[0];
  const int*   ei     = (const int*)d_in[1];
  const float* W      = (const float*)d_in[2];
  const float* a_src  = (const float*)d_in[3];
  const float* a_dst  = (const float*)d_in[4];
  float* out = (float*)d_out;

  const int N = in_sizes[0] / N_IN;     // 50000
  const int E = in_sizes[1] / 2;        // 800000
  const int NB = (N + 1023) / 1024;     // 49 scan chunks

  auto align256 = [](size_t x) { return (x + 255) & ~size_t(255); };
  char* base = (char*)d_ws;
  size_t off = 0;
  __bf16* hp16 = (__bf16*)(base + off);  off += align256((size_t)N * NHD * 2);
  __bf16* WtH  = (__bf16*)(base + off);  off += align256((size_t)N_IN * NHD * 2);
  __bf16* WtL  = (__bf16*)(base + off);  off += align256((size_t)N_IN * NHD * 2);
  float* s       = (float*)(base + off); off += align256((size_t)N * HD * 4);
  float* t       = (float*)(base + off); off += align256((size_t)N * HD * 4);
  int*   deg     = (int*)(base + off);   off += align256((size_t)N * 4);
  int*   partial = (int*)(base + off);   off += align256((size_t)N * 4);
  int*   blocksum= (int*)(base + off);   off += align256((size_t)NB * 4);
  int*   blockoff= (int*)(base + off);   off += align256((size_t)NB * 4);
  int*   row_ptr = (int*)(base + off);   off += align256((size_t)(N + 1) * 4);
  int*   cursor  = (int*)(base + off);   off += align256((size_t)N * 4);
  int*   csr_src = (int*)(base + off);   off += align256((size_t)E * 4);

  // 1. zero deg
  init_kernel<<<(N + 255) / 256, 256, 0, stream>>>(deg, N);
  // 2. split-transpose W
  wsplit_kernel<<<N_IN, NHD, 0, stream>>>(W, WtH, WtL);
  // 3. MFMA GEMM with fused s/t + bf16 hp
  {
    dim3 grid((N + 127) / 128, NHD / 128);
    gemm_mfma_kernel<<<grid, 256, 0, stream>>>(h_ptr, WtH, WtL, a_src, a_dst, hp16, s, t, N);
  }
  // 4. in-degrees
  degree_kernel<<<(E + 255) / 256, 256, 0, stream>>>(ei, deg, E);
  // 5. hierarchical prefix sum -> row_ptr, cursor
  scan1_kernel<<<NB, 256, 0, stream>>>(deg, partial, blocksum, N);
  scan2_kernel<<<1, 64, 0, stream>>>(blocksum, blockoff, &row_ptr[N], NB);
  scan3_kernel<<<NB, 256, 0, stream>>>(partial, blockoff, row_ptr, cursor, N);
  // 6. per-edge scatter (src only)
  scatter_kernel<<<(E + 255) / 256, 256, 0, stream>>>(ei, cursor, csr_src, E);
  // 7. per-dst aggregation (1 wave/node, bf16 gather, 4-deep MLP)
  aggregate_kernel<<<(N + 3) / 4, 256, 0, stream>>>(row_ptr, csr_src, s, t, hp16, out, N);
}

// Round 6
// 291.399 us; speedup vs baseline: 2.3006x; 1.0021x over previous
//
#include <hip/hip_runtime.h>

#define HD 4
#define D 64
#define NHD 256   // HD*D
#define N_IN 256

typedef __attribute__((ext_vector_type(8))) __bf16 bf16x8;
typedef __attribute__((ext_vector_type(4))) __bf16 bf16x4;
typedef __attribute__((ext_vector_type(4))) float f32x4;

constexpr int AROW = 40;   // padded LDS row stride in bf16 (80B = 16B-multiple; 2-way banks = free)

// ---- K1: fused W split-transpose (blocks 0..255) + in-degree count (rest) ----
__global__ __launch_bounds__(256) void pre_kernel(const float* __restrict__ W,
                                                  __bf16* __restrict__ WtH,
                                                  __bf16* __restrict__ WtL,
                                                  const int* __restrict__ ei,
                                                  int* __restrict__ deg, int E) {
  const int b = blockIdx.x;
  if (b < N_IN) {
    const int k = b, n = threadIdx.x;
    float w = W[k * NHD + n];           // coalesced read
    __bf16 hi = (__bf16)w;
    __bf16 lo = (__bf16)(w - (float)hi);
    WtH[n * N_IN + k] = hi;
    WtL[n * N_IN + k] = lo;
  } else {
    const int e = (b - N_IN) * 256 + threadIdx.x;
    if (e < E) atomicAdd(&deg[ei[E + e]], 1);
  }
}

// ---- K2: fused scan pass 1 (blocks 0..NB-1) + MFMA GEMM (rest) ----
// scan1: per-1024-chunk exclusive scan + chunk sums.
// gemm: hp16 = bf16(h @ W) 128x128 tiles, split-B bf16 hi/lo, fused s/t epilogue.
__global__ __launch_bounds__(256) void gemm_scan_kernel(
    const float* __restrict__ A, const __bf16* __restrict__ WtH,
    const __bf16* __restrict__ WtL, const float* __restrict__ a_src,
    const float* __restrict__ a_dst, __bf16* __restrict__ hp16,
    float* __restrict__ s_out, float* __restrict__ t_out, int M,
    const int* __restrict__ deg, int* __restrict__ partial,
    int* __restrict__ blocksum, int NB, int MT) {
  __shared__ __bf16 As[128 * AROW];
  __shared__ __bf16 BsH[128 * AROW];
  __shared__ __bf16 BsL[128 * AROW];
  __shared__ int ws4[4];
  const int tid = threadIdx.x;

  if ((int)blockIdx.x < NB) {
    // ---------------- scan1 ----------------
    const int lane = tid & 63, wv = tid >> 6;
    const int base = blockIdx.x * 1024 + tid * 4;
    const int n = M;
    int v0 = (base + 0 < n) ? deg[base + 0] : 0;
    int v1 = (base + 1 < n) ? deg[base + 1] : 0;
    int v2 = (base + 2 < n) ? deg[base + 2] : 0;
    int v3 = (base + 3 < n) ? deg[base + 3] : 0;
    int sum = v0 + v1 + v2 + v3;
    int incl = sum;
#pragma unroll
    for (int off = 1; off < 64; off <<= 1) {
      int y = __shfl_up(incl, off);
      if (lane >= off) incl += y;
    }
    if (lane == 63) ws4[wv] = incl;
    __syncthreads();
    int wbase = 0;
#pragma unroll
    for (int w = 0; w < 4; ++w)
      if (w < wv) wbase += ws4[w];
    int excl = wbase + incl - sum;
    if (base + 0 < n) partial[base + 0] = excl;
    if (base + 1 < n) partial[base + 1] = excl + v0;
    if (base + 2 < n) partial[base + 2] = excl + v0 + v1;
    if (base + 3 < n) partial[base + 3] = excl + v0 + v1 + v2;
    if (tid == 255) blocksum[blockIdx.x] = wbase + incl;
    return;
  }

  // ---------------- gemm ----------------
  const int g = blockIdx.x - NB;
  const int bx = g % MT, by = g / MT;
  const int lane = tid & 63, wv = tid >> 6;
  const int wr = wv >> 1, wc = wv & 1;
  const int c15 = lane & 15, quad = lane >> 4;
  const int m0 = bx * 128, n0 = by * 128;

  f32x4 acc[4][4];
#pragma unroll
  for (int i = 0; i < 4; ++i)
#pragma unroll
    for (int j = 0; j < 4; ++j) acc[i][j] = (f32x4){0.f, 0.f, 0.f, 0.f};

  const int am = tid >> 1, aks = (tid & 1) * 16;
  const int gr = m0 + am;
  const bool arow_ok = (gr < M);
  const float* Arow = &A[(size_t)gr * N_IN];
  const __bf16* BHrow = &WtH[(size_t)(n0 + am) * N_IN];
  const __bf16* BLrow = &WtL[(size_t)(n0 + am) * N_IN];

  for (int kc = 0; kc < 8; ++kc) {
    const int k0 = kc * 32;
    float4 f0, f1, f2, f3;
    if (arow_ok) {
      f0 = *(const float4*)&Arow[k0 + aks + 0];
      f1 = *(const float4*)&Arow[k0 + aks + 4];
      f2 = *(const float4*)&Arow[k0 + aks + 8];
      f3 = *(const float4*)&Arow[k0 + aks + 12];
    } else {
      f0 = f1 = f2 = f3 = make_float4(0.f, 0.f, 0.f, 0.f);
    }
    bf16x8 bh0 = *(const bf16x8*)&BHrow[k0 + aks];
    bf16x8 bh1 = *(const bf16x8*)&BHrow[k0 + aks + 8];
    bf16x8 bl0 = *(const bf16x8*)&BLrow[k0 + aks];
    bf16x8 bl1 = *(const bf16x8*)&BLrow[k0 + aks + 8];

    __syncthreads();
    bf16x8 a0, a1;
    a0[0] = (__bf16)f0.x; a0[1] = (__bf16)f0.y; a0[2] = (__bf16)f0.z; a0[3] = (__bf16)f0.w;
    a0[4] = (__bf16)f1.x; a0[5] = (__bf16)f1.y; a0[6] = (__bf16)f1.z; a0[7] = (__bf16)f1.w;
    a1[0] = (__bf16)f2.x; a1[1] = (__bf16)f2.y; a1[2] = (__bf16)f2.z; a1[3] = (__bf16)f2.w;
    a1[4] = (__bf16)f3.x; a1[5] = (__bf16)f3.y; a1[6] = (__bf16)f3.z; a1[7] = (__bf16)f3.w;
    *(bf16x8*)&As[am * AROW + aks + 0] = a0;
    *(bf16x8*)&As[am * AROW + aks + 8] = a1;
    *(bf16x8*)&BsH[am * AROW + aks + 0] = bh0;
    *(bf16x8*)&BsH[am * AROW + aks + 8] = bh1;
    *(bf16x8*)&BsL[am * AROW + aks + 0] = bl0;
    *(bf16x8*)&BsL[am * AROW + aks + 8] = bl1;
    __syncthreads();

    bf16x8 af[4], bfh[4], bfl[4];
#pragma unroll
    for (int i = 0; i < 4; ++i) {
      af[i]  = *(bf16x8*)&As[(wr * 64 + i * 16 + c15) * AROW + quad * 8];
      bfh[i] = *(bf16x8*)&BsH[(wc * 64 + i * 16 + c15) * AROW + quad * 8];
      bfl[i] = *(bf16x8*)&BsL[(wc * 64 + i * 16 + c15) * AROW + quad * 8];
    }
#pragma unroll
    for (int mi = 0; mi < 4; ++mi)
#pragma unroll
      for (int ni = 0; ni < 4; ++ni)
        acc[mi][ni] = __builtin_amdgcn_mfma_f32_16x16x32_bf16(af[mi], bfh[ni], acc[mi][ni], 0, 0, 0);
#pragma unroll
    for (int mi = 0; mi < 4; ++mi)
#pragma unroll
      for (int ni = 0; ni < 4; ++ni)
        acc[mi][ni] = __builtin_amdgcn_mfma_f32_16x16x32_bf16(af[mi], bfl[ni], acc[mi][ni], 0, 0, 0);
  }

  const int head = by * 2 + wc;
  float av[4], ad[4];
#pragma unroll
  for (int ni = 0; ni < 4; ++ni) {
    av[ni] = a_src[head * D + ni * 16 + c15];
    ad[ni] = a_dst[head * D + ni * 16 + c15];
  }
  const int row0w = m0 + wr * 64;
#pragma unroll
  for (int mi = 0; mi < 4; ++mi) {
#pragma unroll
    for (int j = 0; j < 4; ++j) {
      float ps = acc[mi][0][j] * av[0] + acc[mi][1][j] * av[1] +
                 acc[mi][2][j] * av[2] + acc[mi][3][j] * av[3];
      float pt = acc[mi][0][j] * ad[0] + acc[mi][1][j] * ad[1] +
                 acc[mi][2][j] * ad[2] + acc[mi][3][j] * ad[3];
#pragma unroll
      for (int m = 1; m < 16; m <<= 1) {
        ps += __shfl_xor(ps, m);
        pt += __shfl_xor(pt, m);
      }
      const int row = row0w + mi * 16 + quad * 4 + j;
      if (c15 == 0 && row < M) {
        s_out[row * HD + head] = ps;
        t_out[row * HD + head] = pt;
      }
    }
#pragma unroll
    for (int ni = 0; ni < 4; ++ni) {
#pragma unroll
      for (int j = 0; j < 4; ++j) {
        const int row = row0w + mi * 16 + quad * 4 + j;
        const int col = n0 + wc * 64 + ni * 16 + c15;
        if (row < M) hp16[(size_t)row * NHD + col] = (__bf16)acc[mi][ni][j];
      }
    }
  }
}

// ---- K3: scan passes 2+3 merged: each block redundantly scans the <=64 blocksums ----
__global__ __launch_bounds__(256) void scan23_kernel(const int* __restrict__ partial,
                                                     const int* __restrict__ blocksum,
                                                     int* __restrict__ row_ptr,
                                                     int* __restrict__ cursor, int n, int NB) {
  __shared__ int s_off;
  const int tid = threadIdx.x;
  if (tid < 64) {
    int v = (tid < NB) ? blocksum[tid] : 0;
    int incl = v;
#pragma unroll
    for (int off = 1; off < 64; off <<= 1) {
      int y = __shfl_up(incl, off);
      if (tid >= off) incl += y;
    }
    // exclusive offset for this block
    int prev = __shfl_up(incl, 1);
    int excl = (tid == 0) ? 0 : prev;
    if (tid == (int)blockIdx.x) s_off = excl;
    if (blockIdx.x == 0 && tid == NB - 1) row_ptr[n] = incl;   // grand total
  }
  __syncthreads();
  const int off = s_off;
  const int base = blockIdx.x * 1024 + tid * 4;
  if (base + 3 < n) {
    int4 p = *(const int4*)&partial[base];
    int4 r = make_int4(p.x + off, p.y + off, p.z + off, p.w + off);
    *(int4*)&row_ptr[base] = r;
    *(int4*)&cursor[base] = r;
  } else {
    for (int j = 0; j < 4; ++j)
      if (base + j < n) {
        int r = partial[base + j] + off;
        row_ptr[base + j] = r;
        cursor[base + j] = r;
      }
  }
}

// ---- K4: per-edge scatter into CSR (src index only) ----
__global__ void scatter_kernel(const int* __restrict__ ei, int* __restrict__ cursor,
                               int* __restrict__ csr_src, int E) {
  int e = blockIdx.x * blockDim.x + threadIdx.x;
  if (e >= E) return;
  int sn = ei[e], dn = ei[E + e];
  int pos = atomicAdd(&cursor[dn], 1);
  csr_src[pos] = sn;
}

// ---- K5: per-dst aggregation: 1 wave/node, 4 dims/lane, 8 gathers in flight ----
__global__ __launch_bounds__(256) void aggregate_kernel(
    const int* __restrict__ row_ptr, const int* __restrict__ csr_src,
    const float* __restrict__ s, const float* __restrict__ t,
    const __bf16* __restrict__ hp16, float* __restrict__ out, int N) {
  const int wave = threadIdx.x >> 6;
  const int lane = threadIdx.x & 63;
  const int node = blockIdx.x * 4 + wave;
  if (node >= N) return;
  const int h = lane >> 4;
  const int d0 = lane * 4;
  const int beg = row_ptr[node], end = row_ptr[node + 1];
  const float tn = t[node * HD + h];
  float num0 = 0.f, num1 = 0.f, num2 = 0.f, num3 = 0.f, den = 0.f;
  int i = beg;
  for (; i + 8 <= end; i += 8) {   // 8 independent gathers (16 loads) in flight
    int sn0 = csr_src[i], sn1 = csr_src[i + 1], sn2 = csr_src[i + 2], sn3 = csr_src[i + 3];
    int sn4 = csr_src[i + 4], sn5 = csr_src[i + 5], sn6 = csr_src[i + 6], sn7 = csr_src[i + 7];
    bf16x4 v0 = *(const bf16x4*)&hp16[(size_t)sn0 * NHD + d0];
    bf16x4 v1 = *(const bf16x4*)&hp16[(size_t)sn1 * NHD + d0];
    bf16x4 v2 = *(const bf16x4*)&hp16[(size_t)sn2 * NHD + d0];
    bf16x4 v3 = *(const bf16x4*)&hp16[(size_t)sn3 * NHD + d0];
    bf16x4 v4 = *(const bf16x4*)&hp16[(size_t)sn4 * NHD + d0];
    bf16x4 v5 = *(const bf16x4*)&hp16[(size_t)sn5 * NHD + d0];
    bf16x4 v6 = *(const bf16x4*)&hp16[(size_t)sn6 * NHD + d0];
    bf16x4 v7 = *(const bf16x4*)&hp16[(size_t)sn7 * NHD + d0];
    float lg0 = s[sn0 * HD + h] + tn, lg1 = s[sn1 * HD + h] + tn;
    float lg2 = s[sn2 * HD + h] + tn, lg3 = s[sn3 * HD + h] + tn;
    float lg4 = s[sn4 * HD + h] + tn, lg5 = s[sn5 * HD + h] + tn;
    float lg6 = s[sn6 * HD + h] + tn, lg7 = s[sn7 * HD + h] + tn;
    lg0 = fmaxf(lg0, 0.2f * lg0); lg1 = fmaxf(lg1, 0.2f * lg1);
    lg2 = fmaxf(lg2, 0.2f * lg2); lg3 = fmaxf(lg3, 0.2f * lg3);
    lg4 = fmaxf(lg4, 0.2f * lg4); lg5 = fmaxf(lg5, 0.2f * lg5);
    lg6 = fmaxf(lg6, 0.2f * lg6); lg7 = fmaxf(lg7, 0.2f * lg7);
    float ex0 = __expf(lg0), ex1 = __expf(lg1), ex2 = __expf(lg2), ex3 = __expf(lg3);
    float ex4 = __expf(lg4), ex5 = __expf(lg5), ex6 = __expf(lg6), ex7 = __expf(lg7);
    den += ((ex0 + ex1) + (ex2 + ex3)) + ((ex4 + ex5) + (ex6 + ex7));
    num0 += ex0 * (float)v0[0] + ex1 * (float)v1[0] + ex2 * (float)v2[0] + ex3 * (float)v3[0]
          + ex4 * (float)v4[0] + ex5 * (float)v5[0] + ex6 * (float)v6[0] + ex7 * (float)v7[0];
    num1 += ex0 * (float)v0[1] + ex1 * (float)v1[1] + ex2 * (float)v2[1] + ex3 * (float)v3[1]
          + ex4 * (float)v4[1] + ex5 * (float)v5[1] + ex6 * (float)v6[1] + ex7 * (float)v7[1];
    num2 += ex0 * (float)v0[2] + ex1 * (float)v1[2] + ex2 * (float)v2[2] + ex3 * (float)v3[2]
          + ex4 * (float)v4[2] + ex5 * (float)v5[2] + ex6 * (float)v6[2] + ex7 * (float)v7[2];
    num3 += ex0 * (float)v0[3] + ex1 * (float)v1[3] + ex2 * (float)v2[3] + ex3 * (float)v3[3]
          + ex4 * (float)v4[3] + ex5 * (float)v5[3] + ex6 * (float)v6[3] + ex7 * (float)v7[3];
  }
  for (; i < end; ++i) {
    int sn0 = csr_src[i];
    bf16x4 v0 = *(const bf16x4*)&hp16[(size_t)sn0 * NHD + d0];
    float lg0 = s[sn0 * HD + h] + tn;
    lg0 = fmaxf(lg0, 0.2f * lg0);
    float ex0 = __expf(lg0);
    den += ex0;
    num0 += ex0 * (float)v0[0];
    num1 += ex0 * (float)v0[1];
    num2 += ex0 * (float)v0[2];
    num3 += ex0 * (float)v0[3];
  }
  const float inv = 1.0f / (den + 1e-16f);
  float4 o = make_float4(num0 * inv, num1 * inv, num2 * inv, num3 * inv);
  *(float4*)&out[(size_t)node * NHD + d0] = o;
}

extern "C" void kernel_launch(void* const* d_in, const int* in_sizes, int n_in,
                              void* d_out, int out_size, void* d_ws, size_t ws_size,
                              hipStream_t stream) {
  const float* h_ptr  = (const float*)d_in[0];
  const int*   ei     = (const int*)d_in[1];
  const float* W      = (const float*)d_in[2];
  const float* a_src  = (const float*)d_in[3];
  const float* a_dst  = (const float*)d_in[4];
  float* out = (float*)d_out;

  const int N = in_sizes[0] / N_IN;     // 50000
  const int E = in_sizes[1] / 2;        // 800000
  const int NB = (N + 1023) / 1024;     // 49 scan chunks
  const int MT = (N + 127) / 128;       // 391 gemm m-tiles

  auto align256 = [](size_t x) { return (x + 255) & ~size_t(255); };
  char* base = (char*)d_ws;
  size_t off = 0;
  __bf16* hp16 = (__bf16*)(base + off);  off += align256((size_t)N * NHD * 2);
  __bf16* WtH  = (__bf16*)(base + off);  off += align256((size_t)N_IN * NHD * 2);
  __bf16* WtL  = (__bf16*)(base + off);  off += align256((size_t)N_IN * NHD * 2);
  float* s       = (float*)(base + off); off += align256((size_t)N * HD * 4);
  float* t       = (float*)(base + off); off += align256((size_t)N * HD * 4);
  int*   deg     = (int*)(base + off);   off += align256((size_t)N * 4);
  int*   partial = (int*)(base + off);   off += align256((size_t)N * 4);
  int*   blocksum= (int*)(base + off);   off += align256((size_t)NB * 4);
  int*   row_ptr = (int*)(base + off);   off += align256((size_t)(N + 1) * 4);
  int*   cursor  = (int*)(base + off);   off += align256((size_t)N * 4);
  int*   csr_src = (int*)(base + off);   off += align256((size_t)E * 4);

  // 0. zero deg (graph-capturable memset node)
  hipMemsetAsync(deg, 0, (size_t)N * 4, stream);
  // 1. fused wsplit + degree
  pre_kernel<<<N_IN + (E + 255) / 256, 256, 0, stream>>>(W, WtH, WtL, ei, deg, E);
  // 2. fused scan1 + MFMA GEMM
  gemm_scan_kernel<<<NB + MT * 2, 256, 0, stream>>>(h_ptr, WtH, WtL, a_src, a_dst,
                                                    hp16, s, t, N, deg, partial,
                                                    blocksum, NB, MT);
  // 3. scan2+3 -> row_ptr, cursor
  scan23_kernel<<<NB, 256, 0, stream>>>(partial, blocksum, row_ptr, cursor, N, NB);
  // 4. per-edge scatter (src only)
  scatter_kernel<<<(E + 255) / 256, 256, 0, stream>>>(ei, cursor, csr_src, E);
  // 5. per-dst aggregation (1 wave/node, bf16 gather, 8-deep MLP)
  aggregate_kernel<<<(N + 3) / 4, 256, 0, stream>>>(row_ptr, csr_src, s, t, hp16, out, N);
}

// Round 7
// 275.323 us; speedup vs baseline: 2.4349x; 1.0584x over previous
//
#include <hip/hip_runtime.h>

#define HD 4
#define D 64
#define NHD 256   // HD*D
#define N_IN 256

typedef __attribute__((ext_vector_type(8))) __bf16 bf16x8;
typedef __attribute__((ext_vector_type(4))) __bf16 bf16x4;
typedef __attribute__((ext_vector_type(4))) float f32x4;

constexpr int AROW = 40;   // padded LDS row stride in bf16 (80B = 16B-multiple; 2-way banks = free)

// ---- K1: fused W transpose->bf16 (blocks 0..255) + XCD-privatized in-degree (rest) ----
__global__ __launch_bounds__(256) void pre_kernel(const float* __restrict__ W,
                                                  __bf16* __restrict__ Wt,
                                                  const int* __restrict__ ei,
                                                  int* __restrict__ deg8, int Nn, int E) {
  const int b = blockIdx.x;
  if (b < N_IN) {
    const int k = b, n = threadIdx.x;
    Wt[n * N_IN + k] = (__bf16)W[k * NHD + n];
  } else {
    const int e = (b - N_IN) * 256 + threadIdx.x;
    const int c = b & 7;   // plane = XCD under round-robin dispatch -> XCD-local atomics
    if (e < E) atomicAdd(&deg8[c * Nn + ei[E + e]], 1);
  }
}

// ---- K2: fused scan pass 1 (blocks 0..NB-1) + MFMA GEMM (rest) ----
__global__ __launch_bounds__(256) void gemm_scan_kernel(
    const float* __restrict__ A, const __bf16* __restrict__ Wt,
    const float* __restrict__ a_src, const float* __restrict__ a_dst,
    __bf16* __restrict__ hp16, float* __restrict__ s_out, float* __restrict__ t_out,
    int M, const int* __restrict__ deg8, int* __restrict__ partial,
    int* __restrict__ blocksum, int NB, int MT) {
  __shared__ __bf16 As[128 * AROW];
  __shared__ __bf16 Bs[128 * AROW];
  __shared__ int ws4[4];
  const int tid = threadIdx.x;

  if ((int)blockIdx.x < NB) {
    // ---------------- scan1: per-1024-node chunk scan of total degrees ----------------
    const int lane = tid & 63, wv = tid >> 6;
    const int base = blockIdx.x * 1024 + tid * 4;
    int v[4];
#pragma unroll
    for (int j = 0; j < 4; ++j) {
      int n = base + j;
      int sum = 0;
      if (n < M) {
#pragma unroll
        for (int c = 0; c < 8; ++c) sum += deg8[c * M + n];
      }
      v[j] = sum;
    }
    int sum = v[0] + v[1] + v[2] + v[3];
    int incl = sum;
#pragma unroll
    for (int off = 1; off < 64; off <<= 1) {
      int y = __shfl_up(incl, off);
      if (lane >= off) incl += y;
    }
    if (lane == 63) ws4[wv] = incl;
    __syncthreads();
    int wbase = 0;
#pragma unroll
    for (int w = 0; w < 4; ++w)
      if (w < wv) wbase += ws4[w];
    int excl = wbase + incl - sum;
    if (base + 0 < M) partial[base + 0] = excl;
    if (base + 1 < M) partial[base + 1] = excl + v[0];
    if (base + 2 < M) partial[base + 2] = excl + v[0] + v[1];
    if (base + 3 < M) partial[base + 3] = excl + v[0] + v[1] + v[2];
    if (tid == 255) blocksum[blockIdx.x] = wbase + incl;
    return;
  }

  // ---------------- gemm: hp16 = bf16(h @ W), 128x128 tile, fused s/t ----------------
  const int g = blockIdx.x - NB;
  const int bx = g % MT, by = g / MT;
  const int lane = tid & 63, wv = tid >> 6;
  const int wr = wv >> 1, wc = wv & 1;
  const int c15 = lane & 15, quad = lane >> 4;
  const int m0 = bx * 128, n0 = by * 128;

  f32x4 acc[4][4];
#pragma unroll
  for (int i = 0; i < 4; ++i)
#pragma unroll
    for (int j = 0; j < 4; ++j) acc[i][j] = (f32x4){0.f, 0.f, 0.f, 0.f};

  const int am = tid >> 1, aks = (tid & 1) * 16;
  const int gr = m0 + am;
  const bool arow_ok = (gr < M);
  const float* Arow = &A[(size_t)gr * N_IN];
  const __bf16* Brow = &Wt[(size_t)(n0 + am) * N_IN];

  for (int kc = 0; kc < 8; ++kc) {
    const int k0 = kc * 32;
    float4 f0, f1, f2, f3;
    if (arow_ok) {
      f0 = *(const float4*)&Arow[k0 + aks + 0];
      f1 = *(const float4*)&Arow[k0 + aks + 4];
      f2 = *(const float4*)&Arow[k0 + aks + 8];
      f3 = *(const float4*)&Arow[k0 + aks + 12];
    } else {
      f0 = f1 = f2 = f3 = make_float4(0.f, 0.f, 0.f, 0.f);
    }
    bf16x8 b0 = *(const bf16x8*)&Brow[k0 + aks];
    bf16x8 b1 = *(const bf16x8*)&Brow[k0 + aks + 8];

    __syncthreads();
    bf16x8 a0, a1;
    a0[0] = (__bf16)f0.x; a0[1] = (__bf16)f0.y; a0[2] = (__bf16)f0.z; a0[3] = (__bf16)f0.w;
    a0[4] = (__bf16)f1.x; a0[5] = (__bf16)f1.y; a0[6] = (__bf16)f1.z; a0[7] = (__bf16)f1.w;
    a1[0] = (__bf16)f2.x; a1[1] = (__bf16)f2.y; a1[2] = (__bf16)f2.z; a1[3] = (__bf16)f2.w;
    a1[4] = (__bf16)f3.x; a1[5] = (__bf16)f3.y; a1[6] = (__bf16)f3.z; a1[7] = (__bf16)f3.w;
    *(bf16x8*)&As[am * AROW + aks + 0] = a0;
    *(bf16x8*)&As[am * AROW + aks + 8] = a1;
    *(bf16x8*)&Bs[am * AROW + aks + 0] = b0;
    *(bf16x8*)&Bs[am * AROW + aks + 8] = b1;
    __syncthreads();

    bf16x8 af[4], bf_[4];
#pragma unroll
    for (int i = 0; i < 4; ++i) {
      af[i]  = *(bf16x8*)&As[(wr * 64 + i * 16 + c15) * AROW + quad * 8];
      bf_[i] = *(bf16x8*)&Bs[(wc * 64 + i * 16 + c15) * AROW + quad * 8];
    }
#pragma unroll
    for (int mi = 0; mi < 4; ++mi)
#pragma unroll
      for (int ni = 0; ni < 4; ++ni)
        acc[mi][ni] = __builtin_amdgcn_mfma_f32_16x16x32_bf16(af[mi], bf_[ni], acc[mi][ni], 0, 0, 0);
  }

  const int head = by * 2 + wc;
  float av[4], ad[4];
#pragma unroll
  for (int ni = 0; ni < 4; ++ni) {
    av[ni] = a_src[head * D + ni * 16 + c15];
    ad[ni] = a_dst[head * D + ni * 16 + c15];
  }
  const int row0w = m0 + wr * 64;
#pragma unroll
  for (int mi = 0; mi < 4; ++mi) {
#pragma unroll
    for (int j = 0; j < 4; ++j) {
      float ps = acc[mi][0][j] * av[0] + acc[mi][1][j] * av[1] +
                 acc[mi][2][j] * av[2] + acc[mi][3][j] * av[3];
      float pt = acc[mi][0][j] * ad[0] + acc[mi][1][j] * ad[1] +
                 acc[mi][2][j] * ad[2] + acc[mi][3][j] * ad[3];
#pragma unroll
      for (int m = 1; m < 16; m <<= 1) {
        ps += __shfl_xor(ps, m);
        pt += __shfl_xor(pt, m);
      }
      const int row = row0w + mi * 16 + quad * 4 + j;
      if (c15 == 0 && row < M) {
        s_out[row * HD + head] = ps;
        t_out[row * HD + head] = pt;
      }
    }
#pragma unroll
    for (int ni = 0; ni < 4; ++ni) {
#pragma unroll
      for (int j = 0; j < 4; ++j) {
        const int row = row0w + mi * 16 + quad * 4 + j;
        const int col = n0 + wc * 64 + ni * 16 + c15;
        if (row < M) hp16[(size_t)row * NHD + col] = (__bf16)acc[mi][ni][j];
      }
    }
  }
}

// ---- K3: scan 2+3: block-offset scan + per-node row_ptr + per-(node,plane) cursors ----
__global__ __launch_bounds__(256) void scan23_kernel(const int* __restrict__ partial,
                                                     const int* __restrict__ blocksum,
                                                     const int* __restrict__ deg8,
                                                     int* __restrict__ row_ptr,
                                                     int* __restrict__ cursor8, int n, int NB) {
  __shared__ int s_off;
  const int tid = threadIdx.x;
  if (tid < 64) {
    int v = (tid < NB) ? blocksum[tid] : 0;
    int incl = v;
#pragma unroll
    for (int off = 1; off < 64; off <<= 1) {
      int y = __shfl_up(incl, off);
      if (tid >= off) incl += y;
    }
    int prev = __shfl_up(incl, 1);
    int excl = (tid == 0) ? 0 : prev;
    if (tid == (int)blockIdx.x) s_off = excl;
    if (blockIdx.x == 0 && tid == NB - 1) row_ptr[n] = incl;   // grand total
  }
  __syncthreads();
  const int off = s_off;
  const int base = blockIdx.x * 1024 + tid * 4;
#pragma unroll
  for (int j = 0; j < 4; ++j) {
    const int node = base + j;
    if (node < n) {
      int rp = partial[node] + off;
      row_ptr[node] = rp;
      int run = rp;
#pragma unroll
      for (int c = 0; c < 8; ++c) {
        cursor8[c * n + node] = run;
        run += deg8[c * n + node];
      }
    }
  }
}

// ---- K4: per-edge scatter into CSR, XCD-privatized cursors ----
__global__ void scatter_kernel(const int* __restrict__ ei, int* __restrict__ cursor8,
                               int* __restrict__ csr_src, int Nn, int E) {
  int e = blockIdx.x * blockDim.x + threadIdx.x;
  if (e >= E) return;
  const int c = blockIdx.x & 7;   // same plane choice as pre_kernel's degree pass
  int sn = ei[e], dn = ei[E + e];
  int pos = atomicAdd(&cursor8[c * Nn + dn], 1);
  csr_src[pos] = sn;
}

// ---- K5: per-dst aggregation: 1 wave/node, 4 dims/lane, 4 gathers in flight ----
__global__ __launch_bounds__(256) void aggregate_kernel(
    const int* __restrict__ row_ptr, const int* __restrict__ csr_src,
    const float* __restrict__ s, const float* __restrict__ t,
    const __bf16* __restrict__ hp16, float* __restrict__ out, int N) {
  const int wave = threadIdx.x >> 6;
  const int lane = threadIdx.x & 63;
  const int node = blockIdx.x * 4 + wave;
  if (node >= N) return;
  const int h = lane >> 4;
  const int d0 = lane * 4;
  const int beg = row_ptr[node], end = row_ptr[node + 1];
  const float tn = t[node * HD + h];
  float num0 = 0.f, num1 = 0.f, num2 = 0.f, num3 = 0.f, den = 0.f;
  int i = beg;
  for (; i + 4 <= end; i += 4) {
    int sn0 = csr_src[i], sn1 = csr_src[i + 1], sn2 = csr_src[i + 2], sn3 = csr_src[i + 3];
    bf16x4 v0 = *(const bf16x4*)&hp16[(size_t)sn0 * NHD + d0];
    bf16x4 v1 = *(const bf16x4*)&hp16[(size_t)sn1 * NHD + d0];
    bf16x4 v2 = *(const bf16x4*)&hp16[(size_t)sn2 * NHD + d0];
    bf16x4 v3 = *(const bf16x4*)&hp16[(size_t)sn3 * NHD + d0];
    float lg0 = s[sn0 * HD + h] + tn;
    float lg1 = s[sn1 * HD + h] + tn;
    float lg2 = s[sn2 * HD + h] + tn;
    float lg3 = s[sn3 * HD + h] + tn;
    lg0 = fmaxf(lg0, 0.2f * lg0);
    lg1 = fmaxf(lg1, 0.2f * lg1);
    lg2 = fmaxf(lg2, 0.2f * lg2);
    lg3 = fmaxf(lg3, 0.2f * lg3);
    float ex0 = __expf(lg0), ex1 = __expf(lg1), ex2 = __expf(lg2), ex3 = __expf(lg3);
    den += (ex0 + ex1) + (ex2 + ex3);
    num0 += ex0 * (float)v0[0] + ex1 * (float)v1[0] + ex2 * (float)v2[0] + ex3 * (float)v3[0];
    num1 += ex0 * (float)v0[1] + ex1 * (float)v1[1] + ex2 * (float)v2[1] + ex3 * (float)v3[1];
    num2 += ex0 * (float)v0[2] + ex1 * (float)v1[2] + ex2 * (float)v2[2] + ex3 * (float)v3[2];
    num3 += ex0 * (float)v0[3] + ex1 * (float)v1[3] + ex2 * (float)v2[3] + ex3 * (float)v3[3];
  }
  for (; i < end; ++i) {
    int sn0 = csr_src[i];
    bf16x4 v0 = *(const bf16x4*)&hp16[(size_t)sn0 * NHD + d0];
    float lg0 = s[sn0 * HD + h] + tn;
    lg0 = fmaxf(lg0, 0.2f * lg0);
    float ex0 = __expf(lg0);
    den += ex0;
    num0 += ex0 * (float)v0[0];
    num1 += ex0 * (float)v0[1];
    num2 += ex0 * (float)v0[2];
    num3 += ex0 * (float)v0[3];
  }
  const float inv = 1.0f / (den + 1e-16f);
  float4 o = make_float4(num0 * inv, num1 * inv, num2 * inv, num3 * inv);
  *(float4*)&out[(size_t)node * NHD + d0] = o;
}

extern "C" void kernel_launch(void* const* d_in, const int* in_sizes, int n_in,
                              void* d_out, int out_size, void* d_ws, size_t ws_size,
                              hipStream_t stream) {
  const float* h_ptr  = (const float*)d_in[0];
  const int*   ei     = (const int*)d_in[1];
  const float* W      = (const float*)d_in[2];
  const float* a_src  = (const float*)d_in[3];
  const float* a_dst  = (const float*)d_in[4];
  float* out = (float*)d_out;

  const int N = in_sizes[0] / N_IN;     // 50000
  const int E = in_sizes[1] / 2;        // 800000
  const int NB = (N + 1023) / 1024;     // 49 scan chunks
  const int MT = (N + 127) / 128;       // 391 gemm m-tiles

  auto align256 = [](size_t x) { return (x + 255) & ~size_t(255); };
  char* base = (char*)d_ws;
  size_t off = 0;
  __bf16* hp16 = (__bf16*)(base + off);  off += align256((size_t)N * NHD * 2);
  __bf16* Wt   = (__bf16*)(base + off);  off += align256((size_t)N_IN * NHD * 2);
  float* s       = (float*)(base + off); off += align256((size_t)N * HD * 4);
  float* t       = (float*)(base + off); off += align256((size_t)N * HD * 4);
  int*   deg8    = (int*)(base + off);   off += align256((size_t)N * 8 * 4);
  int*   cursor8 = (int*)(base + off);   off += align256((size_t)N * 8 * 4);
  int*   partial = (int*)(base + off);   off += align256((size_t)N * 4);
  int*   blocksum= (int*)(base + off);   off += align256((size_t)NB * 4);
  int*   row_ptr = (int*)(base + off);   off += align256((size_t)(N + 1) * 4);
  int*   csr_src = (int*)(base + off);   off += align256((size_t)E * 4);

  // 0. zero privatized degree planes
  hipMemsetAsync(deg8, 0, (size_t)N * 8 * 4, stream);
  // 1. fused W-transpose + privatized degree
  pre_kernel<<<N_IN + (E + 255) / 256, 256, 0, stream>>>(W, Wt, ei, deg8, N, E);
  // 2. fused scan1 + MFMA GEMM (single-B bf16)
  gemm_scan_kernel<<<NB + MT * 2, 256, 0, stream>>>(h_ptr, Wt, a_src, a_dst,
                                                    hp16, s, t, N, deg8, partial,
                                                    blocksum, NB, MT);
  // 3. scan2+3 -> row_ptr + privatized cursors
  scan23_kernel<<<NB, 256, 0, stream>>>(partial, blocksum, deg8, row_ptr, cursor8, N, NB);
  // 4. per-edge scatter (privatized cursors)
  scatter_kernel<<<(E + 255) / 256, 256, 0, stream>>>(ei, cursor8, csr_src, N, E);
  // 5. per-dst aggregation
  aggregate_kernel<<<(N + 3) / 4, 256, 0, stream>>>(row_ptr, csr_src, s, t, hp16, out, N);
}